// Round 13
// baseline (506.091 us; speedup 1.0000x reference)
//
#include <hip/hip_runtime.h>
#include <cstdint>

#define B_    16
#define N_    128
#define P_    4096
#define M_    65536     // B_*P_
#define DIN   1024
#define DHID  512
#define DGEO  128
#define DEMB  200
#define NODEF 328       // DGEO + DEMB
#define NOBJ  151
#define OUTC  50
#define KGEO  656
#define KGEOP 672       // geo K padded to multiple of 32 (BK=32)

typedef __attribute__((ext_vector_type(8))) short bf16x8;
typedef __attribute__((ext_vector_type(4))) float f32x4;

typedef __attribute__((address_space(3))) unsigned char lds_u8;
typedef __attribute__((address_space(1))) unsigned char glb_u8;

static __device__ __forceinline__ void async_copy16(const void* g, void* l) {
  __builtin_amdgcn_global_load_lds((const glb_u8*)g, (lds_u8*)l, 16, 0, 0);
}

static __device__ __forceinline__ unsigned short f2b(float f) {
  union { float f; unsigned u; } v; v.f = f;
  unsigned r = v.u + 0x7fffu + ((v.u >> 16) & 1u);
  return (unsigned short)(r >> 16);
}
static __device__ __forceinline__ float b2f(unsigned short b) {
  union { unsigned u; float f; } v; v.u = ((unsigned)b) << 16;
  return v.f;
}
static __device__ __forceinline__ unsigned pack2(float a, float b) {
  return (unsigned)f2b(a) | ((unsigned)f2b(b) << 16);
}
static __device__ __forceinline__ void unpack8(uint4 raw, float* x) {
  x[0] = b2f(raw.x & 0xffffu); x[1] = b2f(raw.x >> 16);
  x[2] = b2f(raw.y & 0xffffu); x[3] = b2f(raw.y >> 16);
  x[4] = b2f(raw.z & 0xffffu); x[5] = b2f(raw.z >> 16);
  x[6] = b2f(raw.w & 0xffffu); x[7] = b2f(raw.w >> 16);
}

// ---- merged prologue: zero scat + all 4 weight transposes in one launch ----
#define ZN   131072                    // scat zero, uint4 count (2 MB)
#define TV   (512 * 1024)
#define TG   (512 * KGEOP)
#define TF   (512 * 1024)
#define TC   (128 * 512)
#define PREP_TOT (ZN + TV + TG + TF + TC)
__global__ __launch_bounds__(256)
void prep_kernel(uint4* __restrict__ scat,
                 const float* __restrict__ vis_w, unsigned short* __restrict__ wT_vis,
                 const float* __restrict__ geo_w, unsigned short* __restrict__ wT_geo,
                 const float* __restrict__ fus_w, unsigned short* __restrict__ wT_fus,
                 const float* __restrict__ cls_w, unsigned short* __restrict__ wT_cls) {
  int idx = blockIdx.x * 256 + threadIdx.x;
  if (idx < ZN) { scat[idx] = make_uint4(0, 0, 0, 0); return; }
  idx -= ZN;
  if (idx < TV) {
    int n = idx >> 10, k = idx & 1023;
    wT_vis[idx] = f2b(vis_w[(size_t)k * 512 + n]);
    return;
  }
  idx -= TV;
  if (idx < TG) {
    int n = idx / KGEOP, k = idx - n * KGEOP;
    wT_geo[idx] = (k < KGEO) ? f2b(geo_w[(size_t)k * 512 + n]) : 0;
    return;
  }
  idx -= TG;
  if (idx < TF) {
    int n = idx >> 10, k = idx & 1023;
    wT_fus[idx] = f2b(fus_w[(size_t)k * 512 + n]);
    return;
  }
  idx -= TF;
  if (idx < TC) {
    int n = idx >> 9, k = idx & 511;
    wT_cls[idx] = (n < OUTC) ? f2b(cls_w[(size_t)k * OUTC + n]) : 0;
  }
}

// ---- per-node features (relu'd, bf16) ----
__global__ __launch_bounds__(128)
void node_kernel(const float* __restrict__ box, const float* __restrict__ plog,
                 const float* __restrict__ semw,
                 const float* __restrict__ w1, const float* __restrict__ b1,
                 const float* __restrict__ w2, const float* __restrict__ b2,
                 unsigned short* __restrict__ nodeFb) {
  const int node = blockIdx.x;
  const int t = threadIdx.x;
  __shared__ float sBox[9];
  __shared__ float sH[128];
  __shared__ float sE[NOBJ];
  __shared__ float sRed[4];
  if (t < 9) sBox[t] = box[node * 9 + t];
  float l0 = (t < NOBJ) ? plog[node * NOBJ + t] : -1e30f;
  float l1 = (t + 128 < NOBJ) ? plog[node * NOBJ + t + 128] : -1e30f;
  __syncthreads();
  float h = b1[t];
#pragma unroll
  for (int i = 0; i < 9; i++) h = fmaf(sBox[i], w1[i * 128 + t], h);
  h = fmaxf(h, 0.f);
  sH[t] = h;
  float mx = fmaxf(l0, l1);
#pragma unroll
  for (int off = 32; off >= 1; off >>= 1) mx = fmaxf(mx, __shfl_xor(mx, off));
  if ((t & 63) == 0) sRed[t >> 6] = mx;
  __syncthreads();
  mx = fmaxf(sRed[0], sRed[1]);
  float e0 = (t < NOBJ) ? expf(l0 - mx) : 0.f;
  float e1 = (t + 128 < NOBJ) ? expf(l1 - mx) : 0.f;
  if (t < NOBJ) sE[t] = e0;
  if (t + 128 < NOBJ) sE[t + 128] = e1;
  float sm = e0 + e1;
#pragma unroll
  for (int off = 32; off >= 1; off >>= 1) sm += __shfl_xor(sm, off);
  if ((t & 63) == 0) sRed[2 + (t >> 6)] = sm;
  __syncthreads();
  const float inv = 1.f / (sRed[2] + sRed[3]);
  float pv = b2[t];
  for (int i = 0; i < 128; i++) pv = fmaf(sH[i], w2[i * 128 + t], pv);
  nodeFb[(size_t)node * NODEF + t] = f2b(fmaxf(pv, 0.f));
  float a0 = 0.f, a1 = 0.f;
  const int d1 = (t + 128 < DEMB) ? (t + 128) : 0;
  for (int i = 0; i < NOBJ; i++) {
    float e = sE[i];
    a0 = fmaf(e, semw[i * DEMB + t], a0);
    a1 = fmaf(e, semw[i * DEMB + d1], a1);
  }
  nodeFb[(size_t)node * NODEF + 128 + t] = f2b(fmaxf(a0 * inv, 0.f));
  if (t + 128 < DEMB) nodeFb[(size_t)node * NODEF + 128 + t + 128] = f2b(fmaxf(a1 * inv, 0.f));
}

// ---- relu + f32->bf16 cast (measured ~85% HBM) ----
__global__ __launch_bounds__(256)
void relu_cast_kernel(const float* __restrict__ in, unsigned short* __restrict__ out, int n8) {
  for (int i = blockIdx.x * blockDim.x + threadIdx.x; i < n8; i += gridDim.x * blockDim.x) {
    float4 v0 = ((const float4*)in)[2 * i];
    float4 v1 = ((const float4*)in)[2 * i + 1];
    uint4 u;
    u.x = pack2(fmaxf(v0.x, 0.f), fmaxf(v0.y, 0.f));
    u.y = pack2(fmaxf(v0.z, 0.f), fmaxf(v0.w, 0.f));
    u.z = pack2(fmaxf(v1.x, 0.f), fmaxf(v1.y, 0.f));
    u.w = pack2(fmaxf(v1.z, 0.f), fmaxf(v1.w, 0.f));
    ((uint4*)out)[i] = u;
  }
}

// ---- fused LayerNorm + ReLU, in place, wave per row ----
template<int D>
__global__ __launch_bounds__(256)
void ln_relu_kernel(unsigned short* __restrict__ X,
                    const float* __restrict__ g, const float* __restrict__ bta) {
  constexpr int C = D / 64;
  const int lane = threadIdx.x & 63, wv = threadIdx.x >> 6;
  const size_t row = (size_t)blockIdx.x * 4 + wv;
  unsigned short* xp = X + row * D + lane * C;
  float x[C];
#pragma unroll
  for (int c = 0; c < C; c += 8) {
    uint4 raw = *(const uint4*)(xp + c);
    unpack8(raw, x + c);
  }
  float s = 0.f, s2 = 0.f;
#pragma unroll
  for (int q = 0; q < C; q++) { s += x[q]; s2 = fmaf(x[q], x[q], s2); }
#pragma unroll
  for (int off = 32; off >= 1; off >>= 1) { s += __shfl_xor(s, off); s2 += __shfl_xor(s2, off); }
  const float mu = s / D;
  const float rs = rsqrtf(s2 / D - mu * mu + 1e-5f);
  const float* gp = g + lane * C;
  const float* bp = bta + lane * C;
#pragma unroll
  for (int c = 0; c < C; c += 8) {
    float4 g0 = *(const float4*)(gp + c), g1 = *(const float4*)(gp + c + 4);
    float4 t0 = *(const float4*)(bp + c), t1 = *(const float4*)(bp + c + 4);
    float y0 = fmaxf(fmaf((x[c + 0] - mu) * rs, g0.x, t0.x), 0.f);
    float y1 = fmaxf(fmaf((x[c + 1] - mu) * rs, g0.y, t0.y), 0.f);
    float y2 = fmaxf(fmaf((x[c + 2] - mu) * rs, g0.z, t0.z), 0.f);
    float y3 = fmaxf(fmaf((x[c + 3] - mu) * rs, g0.w, t0.w), 0.f);
    float y4 = fmaxf(fmaf((x[c + 4] - mu) * rs, g1.x, t1.x), 0.f);
    float y5 = fmaxf(fmaf((x[c + 5] - mu) * rs, g1.y, t1.y), 0.f);
    float y6 = fmaxf(fmaf((x[c + 6] - mu) * rs, g1.z, t1.z), 0.f);
    float y7 = fmaxf(fmaf((x[c + 7] - mu) * rs, g1.w, t1.w), 0.f);
    uint4 u;
    u.x = pack2(y0, y1); u.y = pack2(y2, y3);
    u.z = pack2(y4, y5); u.w = pack2(y6, y7);
    *(uint4*)(xp + c) = u;
  }
}

// ---- full-width 64x512 GEMM v2: A gload_lds ring-4, B gload_lds ring-2 ----
// 512 thr (8 waves, 2M x 4N), BK=32. LDS = A 4x4K + B 2x32K = 80 KB -> 2 blocks/CU.
// All staging via global_load_lds (linear dest) with gemm256r's measured-0-conflict
// source/read swizzle pair: slot q of row/col r holds src kslot q^((r>>1)&3);
// reader uses koff = ((lane>>4) ^ ((frow>>1)&3)) << 4.
// Per-phase vm events: waves 0-3 stage A(s+4) [1] + B(s+2) [4] = 5; waves 4-7: B only [4].
// Ledger (per wave class, oldest-first; prologue A0..A3,B0,B1):
//   waves 0-3: head of s needs A(s) [issued s-4] & B(s) [s-2]; newer-than-B(s) =
//     phase s-1's [A(s+3) if s+3<NS] + [B(s+1) if s+1<NS] -> s==0: 4 (only B1 newer);
//     steady: 5; s in {NS-3, NS-2}: 4 (A stream ended); s==NS-1: 0.
//   waves 4-7: newer-than-B(s) = B(s+1) -> 4; s==NS-1: 0.
// WAR: stage(s+4)/(s+2) overwrite slots whose readers passed this phase's 2nd barrier.
// MODE 0: A plain bf16 [M][ldaE]. MODE 2: A per-lane gathered pair rows from nodeFb.
template<int MODE>
__global__ __launch_bounds__(512, 4)
void gemmW2(const unsigned short* __restrict__ A, int ldaE,
            const unsigned short* __restrict__ Bt, int Ktot,
            const float* __restrict__ bias,
            unsigned short* __restrict__ C, int ldcE, int ccol0,
            const int* __restrict__ pidx,
            const unsigned short* __restrict__ nodeFb,
            const unsigned short* __restrict__ zsrc) {
  const int NS = Ktot >> 5;
  __shared__ __align__(16) unsigned char smem[16384 + 65536];  // A 4x4K | B 2x32K
  const int tid = threadIdx.x, lane = tid & 63, w = tid >> 6;
  const int bm = blockIdx.x;

  // ---- A staging (waves 0-3, one 16B gload_lds per wave per stage) ----
  // wave w covers rows w*16 + (lane>>2); lds slot lane&3 <- src kslot (lane&3)^((lane>>3)&3)
  const unsigned short* aS = nullptr;   // per-lane source base (+ s*32 elems per stage)
  const unsigned short* nbS = nullptr;
  const unsigned short* nbO = nullptr;
  int aslot8 = 0;
  if (w < 4) {
    const int arow = w * 16 + (lane >> 2);
    const int aslot = (lane & 3) ^ ((lane >> 3) & 3);
    aslot8 = aslot * 8;
    if (MODE == 0) {
      aS = A + (size_t)(bm * 64 + arow) * ldaE + aslot8;
    } else {
      int pr = bm * 64 + arow;
      int2 so = *(const int2*)(pidx + 2 * pr);
      int b = pr >> 12;
      nbS = nodeFb + (size_t)((b << 7) + so.x) * NODEF;
      nbO = nodeFb + (size_t)((b << 7) + so.y) * NODEF;
    }
  }
  auto stageA = [&](int s) {
    if (w < 4) {
      unsigned char* la = smem + (s & 3) * 4096 + w * 1024;
      if (MODE == 0) {
        async_copy16(aS + (size_t)s * 32, la);
      } else {
        const int e = s * 32 + aslot8;
        uintptr_t sel = (e < NODEF) ? (uintptr_t)(nbS + e)
                      : (e < KGEO)  ? (uintptr_t)(nbO + (e - NODEF))
                                    : (uintptr_t)zsrc;
        async_copy16((const void*)sel, la);
      }
    }
  };

  // ---- B staging: wave w, instr i covers chunk c=w*4+i (16 cols x 64B) ----
  const unsigned char* bBase = (const unsigned char*)Bt;
  const int gsB = (lane & 3) ^ ((lane >> 3) & 3);
  int bOff[4];
#pragma unroll
  for (int i = 0; i < 4; i++) {
    int col = (w * 4 + i) * 16 + (lane >> 2);
    bOff[i] = col * Ktot * 2 + gsB * 16;
  }
  auto stageB = [&](int s) {
    unsigned char* lb = smem + 16384 + (s & 1) * 32768 + w * 4096;
#pragma unroll
    for (int i = 0; i < 4; i++)
      async_copy16(bBase + (size_t)bOff[i] + (size_t)s * 64, lb + i * 1024);
  };

  // ---- fragment geometry (wave: 32 rows x 128 cols) ----
  const int wm = w >> 2, wn = w & 3;
  const int frow = lane & 15;
  const int koff = (((lane >> 4) ^ ((frow >> 1) & 3)) << 4);
  const int aRowB = (wm * 32 + frow) * 64;
  const int bColB = (wn * 128 + frow) * 64;

  f32x4 acc[2][8];
#pragma unroll
  for (int m = 0; m < 2; m++)
#pragma unroll
    for (int n = 0; n < 8; n++) acc[m][n] = (f32x4){0.f, 0.f, 0.f, 0.f};

  stageA(0); stageA(1); stageA(2); stageA(3);
  stageB(0); stageB(1);

#pragma unroll 1
  for (int sc = 0; sc < NS; ++sc) {
    if (sc == NS - 1)
      asm volatile("s_waitcnt vmcnt(0)" ::: "memory");
    else if (w >= 4 || sc == 0 || sc >= NS - 3)
      asm volatile("s_waitcnt vmcnt(4)" ::: "memory");
    else
      asm volatile("s_waitcnt vmcnt(5)" ::: "memory");
    __builtin_amdgcn_s_barrier();
    __builtin_amdgcn_sched_barrier(0);
    const unsigned char* ab = smem + (sc & 3) * 4096;
    const unsigned char* bb = smem + 16384 + (sc & 1) * 32768;
    bf16x8 af0 = *(const bf16x8*)(ab + aRowB + koff);
    bf16x8 af1 = *(const bf16x8*)(ab + aRowB + 16 * 64 + koff);
    __builtin_amdgcn_s_setprio(1);
#pragma unroll
    for (int n = 0; n < 8; n++) {
      bf16x8 bf = *(const bf16x8*)(bb + bColB + n * 16 * 64 + koff);
      acc[0][n] = __builtin_amdgcn_mfma_f32_16x16x32_bf16(af0, bf, acc[0][n], 0, 0, 0);
      acc[1][n] = __builtin_amdgcn_mfma_f32_16x16x32_bf16(af1, bf, acc[1][n], 0, 0, 0);
    }
    __builtin_amdgcn_s_setprio(0);
    __builtin_amdgcn_sched_barrier(0);
    __builtin_amdgcn_s_barrier();               // all reads of slots (sc&3),(sc&1) done
    __builtin_amdgcn_sched_barrier(0);
    if (sc + 4 < NS) stageA(sc + 4);            // overwrites A slot sc&3 safely
    if (sc + 2 < NS) stageB(sc + 2);            // overwrites B slot sc&1 safely
  }
  // ---- epilogue: C/D layout col=lane&15, row=(lane>>4)*4+i ----
  const int rb = bm * 64 + wm * 32 + ((lane >> 4) << 2);
  const int cb = wn * 128 + frow;
#pragma unroll
  for (int n = 0; n < 8; n++) {
    const int col = cb + n * 16;
    const float bv = bias[col];
#pragma unroll
    for (int m = 0; m < 2; m++)
#pragma unroll
      for (int i = 0; i < 4; i++) {
        const int row = rb + m * 16 + i;
        C[(size_t)row * ldcE + ccol0 + col] = f2b(acc[m][n][i] + bv);
      }
  }
}

// ---- 128x128 m97-structure GEMM for cls layer (N=50) + fused score scatter ----
__global__ __launch_bounds__(256)
void gemm_cls(const unsigned short* __restrict__ A, int lda,
              const unsigned short* __restrict__ Bt,
              const float* __restrict__ bias,
              float* __restrict__ C,
              int Ktot,
              const int* __restrict__ pidx,
              unsigned long long* __restrict__ scat) {
  __shared__ unsigned short ldsA[128 * 64];
  __shared__ unsigned short ldsB[128 * 64];
  const int tid = threadIdx.x;
  const int lane = tid & 63, wid = tid >> 6;
  const int cpx = gridDim.x >> 3;
  const int bm = (blockIdx.x & 7) * cpx + (blockIdx.x >> 3);

  const int srow = wid * 32 + (lane >> 3);
  const int skof = (lane & 7) * 8;
  const unsigned short* ag = A + (size_t)(bm * 128 + srow) * lda + skof;
  const unsigned short* bg = Bt + (size_t)srow * Ktot + skof;

  f32x4 acc[4][4];
#pragma unroll
  for (int m = 0; m < 4; m++)
#pragma unroll
    for (int n = 0; n < 4; n++) acc[m][n] = (f32x4){0.f, 0.f, 0.f, 0.f};

  const int wm = wid >> 1, wn = wid & 1;
  const int frow = lane & 15;
  const int kgrp = (lane >> 4) << 3;

  for (int kt = 0; kt < Ktot; kt += 64) {
#pragma unroll
    for (int i = 0; i < 4; i++) {
      async_copy16(ag + (size_t)i * 8 * lda + kt, &ldsA[wid * 2048 + i * 512]);
      async_copy16(bg + (size_t)i * 8 * Ktot + kt, &ldsB[wid * 2048 + i * 512]);
    }
    __syncthreads();
#pragma unroll
    for (int kk = 0; kk < 64; kk += 32) {
      bf16x8 af[4], bfr[4];
#pragma unroll
      for (int m = 0; m < 4; m++)
        af[m] = *(const bf16x8*)&ldsA[(wm * 64 + m * 16 + frow) * 64 + kk + kgrp];
#pragma unroll
      for (int n = 0; n < 4; n++)
        bfr[n] = *(const bf16x8*)&ldsB[(wn * 64 + n * 16 + frow) * 64 + kk + kgrp];
#pragma unroll
      for (int m = 0; m < 4; m++)
#pragma unroll
        for (int n = 0; n < 4; n++)
          acc[m][n] = __builtin_amdgcn_mfma_f32_16x16x32_bf16(af[m], bfr[n], acc[m][n], 0, 0, 0);
    }
    __syncthreads();
  }
  const int rb = bm * 128 + wm * 64 + ((lane >> 4) << 2);
#pragma unroll
  for (int n = 0; n < 4; n++) {
    const int col = wn * 64 + frow + n * 16;
    const float bv = (col < OUTC) ? bias[col] : 0.f;
#pragma unroll
    for (int m = 0; m < 4; m++)
#pragma unroll
      for (int i = 0; i < 4; i++) {
        const int row = rb + m * 16 + i;
        if (col < OUTC) C[(size_t)row * OUTC + col] = acc[m][n][i] + bv;
      }
  }
  if (wn == 0) {
#pragma unroll
    for (int m = 0; m < 4; m++)
#pragma unroll
      for (int i = 0; i < 4; i++) {
        float mx = -1e30f;
#pragma unroll
        for (int n = 0; n < 4; n++) {
          const int col = n * 16 + frow;
          float v = acc[m][n][i] + ((col < OUTC) ? bias[col] : 0.f);
          if (col < OUTC) mx = fmaxf(mx, v);
        }
        mx = fmaxf(mx, __shfl_xor(mx, 1));
        mx = fmaxf(mx, __shfl_xor(mx, 2));
        mx = fmaxf(mx, __shfl_xor(mx, 4));
        mx = fmaxf(mx, __shfl_xor(mx, 8));
        if (frow == 0) {
          const int row = rb + m * 16 + i;
          float sc = 1.f / (1.f + expf(-mx));
          int b = row >> 12, p = row & 4095;
          int s = pidx[2 * row], o = pidx[2 * row + 1];
          unsigned long long key = (((unsigned long long)(p + 1)) << 32) |
                                   (unsigned long long)__float_as_uint(sc);
          atomicMax(&scat[((size_t)(b * N_ + s) << 7) + o], key);
        }
      }
  }
}

__global__ void relmat_kernel(const unsigned long long* __restrict__ scat, float* __restrict__ out) {
  int i = blockIdx.x * blockDim.x + threadIdx.x;
  if (i >= B_ * N_ * N_) return;
  unsigned long long v = scat[i];
  out[i] = v ? __uint_as_float((unsigned)(v & 0xffffffffu)) : 0.f;
}

extern "C" void kernel_launch(void* const* d_in, const int* in_sizes, int n_in,
                              void* d_out, int out_size, void* d_ws, size_t ws_size,
                              hipStream_t stream) {
  const float* visual_feat = (const float*)d_in[0];
  const float* box_info    = (const float*)d_in[1];
  const float* pred_logits = (const float*)d_in[2];
  const int*   pair_idx    = (const int*)d_in[3];
  const float* obj_sem_w   = (const float*)d_in[4];
  const float* pos_w1 = (const float*)d_in[5];
  const float* pos_b1 = (const float*)d_in[6];
  const float* pos_w2 = (const float*)d_in[7];
  const float* pos_b2 = (const float*)d_in[8];
  const float* vis_w  = (const float*)d_in[9];
  const float* vis_b  = (const float*)d_in[10];
  const float* geo_w  = (const float*)d_in[11];
  const float* geo_b  = (const float*)d_in[12];
  const float* fus_g  = (const float*)d_in[13];
  const float* fus_bt = (const float*)d_in[14];
  const float* fus_w  = (const float*)d_in[15];
  const float* fus_b  = (const float*)d_in[16];
  const float* cls_g  = (const float*)d_in[17];
  const float* cls_bt = (const float*)d_in[18];
  const float* cls_w  = (const float*)d_in[19];
  const float* cls_b  = (const float*)d_in[20];

  char* ws = (char*)d_ws;
  size_t off = 0;
  auto alloc = [&](size_t bytes) { char* p = ws + off; off += (bytes + 255) & ~(size_t)255; return p; };
  unsigned short* fused = (unsigned short*)alloc((size_t)M_ * 1024 * 2);      // 134 MB
  unsigned short* R1    = (unsigned short*)alloc((size_t)M_ * 1024 * 2);      // 134 MB: visA -> fused2
  unsigned short* nodeFb = (unsigned short*)alloc((size_t)B_ * N_ * NODEF * 2);
  unsigned short* wT_vis = (unsigned short*)alloc((size_t)512 * 1024 * 2);
  unsigned short* wT_geo = (unsigned short*)alloc((size_t)512 * KGEOP * 2);
  unsigned short* wT_fus = (unsigned short*)alloc((size_t)512 * 1024 * 2);
  unsigned short* wT_cls = (unsigned short*)alloc((size_t)128 * 512 * 2);
  unsigned long long* scat = (unsigned long long*)alloc((size_t)B_ * N_ * N_ * 8);

  unsigned short* visA   = R1;      // [M][1024] bf16 (consumed by vis GEMM)
  unsigned short* fused2 = R1;      // [M][512]  (written by fus GEMM afterwards)

  float* out_logits = (float*)d_out;
  float* out_rel = out_logits + (size_t)M_ * OUTC;

  prep_kernel<<<dim3((PREP_TOT + 255) / 256), 256, 0, stream>>>(
      (uint4*)scat, vis_w, wT_vis, geo_w, wT_geo, fus_w, wT_fus, cls_w, wT_cls);
  node_kernel<<<dim3(B_ * N_), 128, 0, stream>>>(box_info, pred_logits, obj_sem_w,
                                                 pos_w1, pos_b1, pos_w2, pos_b2, nodeFb);
  // geo: gather GEMM (A L2-resident) -> fused[:,512:]
  gemmW2<2><<<dim3(M_ / 64), 512, 0, stream>>>(nullptr, 0, wT_geo, KGEOP, geo_b,
                                               fused, 1024, 512,
                                               pair_idx, nodeFb, (const unsigned short*)scat);
  // vis: relu_cast (HBM-ceiling) + plain GEMM -> fused[:,0:512]
  relu_cast_kernel<<<dim3(2048), 256, 0, stream>>>(visual_feat, visA, M_ * 1024 / 8);
  gemmW2<0><<<dim3(M_ / 64), 512, 0, stream>>>(visA, 1024, wT_vis, 1024, vis_b,
                                               fused, 1024, 0,
                                               nullptr, nullptr, nullptr);
  ln_relu_kernel<1024><<<dim3(M_ / 4), 256, 0, stream>>>(fused, fus_g, fus_bt);
  // fus: plain GEMM -> fused2
  gemmW2<0><<<dim3(M_ / 64), 512, 0, stream>>>(fused, 1024, wT_fus, 1024, fus_b,
                                               fused2, 512, 0,
                                               nullptr, nullptr, nullptr);
  ln_relu_kernel<512><<<dim3(M_ / 4), 256, 0, stream>>>(fused2, cls_g, cls_bt);
  gemm_cls<<<dim3(512), 256, 0, stream>>>(fused2, 512, wT_cls, cls_b,
                                          out_logits, 512, pair_idx, scat);
  relmat_kernel<<<dim3((B_ * N_ * N_) / 256), 256, 0, stream>>>(scat, out_rel);
}

// Round 14
// 443.879 us; speedup vs baseline: 1.1402x; 1.1402x over previous
//
#include <hip/hip_runtime.h>
#include <cstdint>

#define B_    16
#define N_    128
#define P_    4096
#define M_    65536     // B_*P_
#define DIN   1024
#define DHID  512
#define DGEO  128
#define DEMB  200
#define NODEF 328       // DGEO + DEMB
#define NOBJ  151
#define OUTC  50
#define KGEO  656
#define KGEOP 672       // geo K padded to multiple of 32 (ring BK=32)

typedef __attribute__((ext_vector_type(8))) short bf16x8;
typedef __attribute__((ext_vector_type(4))) float f32x4;

typedef __attribute__((address_space(3))) unsigned char lds_u8;
typedef __attribute__((address_space(1))) unsigned char glb_u8;

static __device__ __forceinline__ void async_copy16(const void* g, void* l) {
  __builtin_amdgcn_global_load_lds((const glb_u8*)g, (lds_u8*)l, 16, 0, 0);
}

static __device__ __forceinline__ unsigned short f2b(float f) {
  union { float f; unsigned u; } v; v.f = f;
  unsigned r = v.u + 0x7fffu + ((v.u >> 16) & 1u);
  return (unsigned short)(r >> 16);
}
static __device__ __forceinline__ float b2f(unsigned short b) {
  union { unsigned u; float f; } v; v.u = ((unsigned)b) << 16;
  return v.f;
}
static __device__ __forceinline__ unsigned pack2(float a, float b) {
  return (unsigned)f2b(a) | ((unsigned)f2b(b) << 16);
}
static __device__ __forceinline__ void unpack8(uint4 raw, float* x) {
  x[0] = b2f(raw.x & 0xffffu); x[1] = b2f(raw.x >> 16);
  x[2] = b2f(raw.y & 0xffffu); x[3] = b2f(raw.y >> 16);
  x[4] = b2f(raw.z & 0xffffu); x[5] = b2f(raw.z >> 16);
  x[6] = b2f(raw.w & 0xffffu); x[7] = b2f(raw.w >> 16);
}

// ---- merged prologue: zero scat + all 4 weight transposes in one launch ----
#define ZN   131072                    // scat zero, uint4 count (2 MB)
#define TV   (512 * 1024)              // wT_vis elems
#define TG   (512 * KGEOP)             // wT_geo elems
#define TF   (512 * 1024)              // wT_fus elems
#define TC   (128 * 512)               // wT_cls elems
#define PREP_TOT (ZN + TV + TG + TF + TC)
__global__ __launch_bounds__(256)
void prep_kernel(uint4* __restrict__ scat,
                 const float* __restrict__ vis_w, unsigned short* __restrict__ wT_vis,
                 const float* __restrict__ geo_w, unsigned short* __restrict__ wT_geo,
                 const float* __restrict__ fus_w, unsigned short* __restrict__ wT_fus,
                 const float* __restrict__ cls_w, unsigned short* __restrict__ wT_cls) {
  int idx = blockIdx.x * 256 + threadIdx.x;
  if (idx < ZN) { scat[idx] = make_uint4(0, 0, 0, 0); return; }
  idx -= ZN;
  if (idx < TV) {
    int n = idx >> 10, k = idx & 1023;
    wT_vis[idx] = f2b(vis_w[(size_t)k * 512 + n]);
    return;
  }
  idx -= TV;
  if (idx < TG) {
    int n = idx / KGEOP, k = idx - n * KGEOP;
    wT_geo[idx] = (k < KGEO) ? f2b(geo_w[(size_t)k * 512 + n]) : 0;
    return;
  }
  idx -= TG;
  if (idx < TF) {
    int n = idx >> 10, k = idx & 1023;
    wT_fus[idx] = f2b(fus_w[(size_t)k * 512 + n]);
    return;
  }
  idx -= TF;
  if (idx < TC) {
    int n = idx >> 9, k = idx & 511;
    wT_cls[idx] = (n < OUTC) ? f2b(cls_w[(size_t)k * OUTC + n]) : 0;
  }
}

// ---- per-node features (relu'd, bf16): nodeFb[node] = [relu(pos)(128), relu(sem)(200)] ----
__global__ __launch_bounds__(128)
void node_kernel(const float* __restrict__ box, const float* __restrict__ plog,
                 const float* __restrict__ semw,
                 const float* __restrict__ w1, const float* __restrict__ b1,
                 const float* __restrict__ w2, const float* __restrict__ b2,
                 unsigned short* __restrict__ nodeFb) {
  const int node = blockIdx.x;
  const int t = threadIdx.x;
  __shared__ float sBox[9];
  __shared__ float sH[128];
  __shared__ float sE[NOBJ];
  __shared__ float sRed[4];
  if (t < 9) sBox[t] = box[node * 9 + t];
  float l0 = (t < NOBJ) ? plog[node * NOBJ + t] : -1e30f;
  float l1 = (t + 128 < NOBJ) ? plog[node * NOBJ + t + 128] : -1e30f;
  __syncthreads();
  float h = b1[t];
#pragma unroll
  for (int i = 0; i < 9; i++) h = fmaf(sBox[i], w1[i * 128 + t], h);
  h = fmaxf(h, 0.f);
  sH[t] = h;
  float mx = fmaxf(l0, l1);
#pragma unroll
  for (int off = 32; off >= 1; off >>= 1) mx = fmaxf(mx, __shfl_xor(mx, off));
  if ((t & 63) == 0) sRed[t >> 6] = mx;
  __syncthreads();
  mx = fmaxf(sRed[0], sRed[1]);
  float e0 = (t < NOBJ) ? expf(l0 - mx) : 0.f;
  float e1 = (t + 128 < NOBJ) ? expf(l1 - mx) : 0.f;
  if (t < NOBJ) sE[t] = e0;
  if (t + 128 < NOBJ) sE[t + 128] = e1;
  float sm = e0 + e1;
#pragma unroll
  for (int off = 32; off >= 1; off >>= 1) sm += __shfl_xor(sm, off);
  if ((t & 63) == 0) sRed[2 + (t >> 6)] = sm;
  __syncthreads();
  const float inv = 1.f / (sRed[2] + sRed[3]);
  float pv = b2[t];
  for (int i = 0; i < 128; i++) pv = fmaf(sH[i], w2[i * 128 + t], pv);
  nodeFb[(size_t)node * NODEF + t] = f2b(fmaxf(pv, 0.f));
  float a0 = 0.f, a1 = 0.f;
  const int d1 = (t + 128 < DEMB) ? (t + 128) : 0;
  for (int i = 0; i < NOBJ; i++) {
    float e = sE[i];
    a0 = fmaf(e, semw[i * DEMB + t], a0);
    a1 = fmaf(e, semw[i * DEMB + d1], a1);
  }
  nodeFb[(size_t)node * NODEF + 128 + t] = f2b(fmaxf(a0 * inv, 0.f));
  if (t + 128 < DEMB) nodeFb[(size_t)node * NODEF + 128 + t + 128] = f2b(fmaxf(a1 * inv, 0.f));
}

// ---- fused LayerNorm + ReLU, in place, wave per row ----
template<int D>
__global__ __launch_bounds__(256)
void ln_relu_kernel(unsigned short* __restrict__ X,
                    const float* __restrict__ g, const float* __restrict__ bta) {
  constexpr int C = D / 64;
  const int lane = threadIdx.x & 63, wv = threadIdx.x >> 6;
  const size_t row = (size_t)blockIdx.x * 4 + wv;
  unsigned short* xp = X + row * D + lane * C;
  float x[C];
#pragma unroll
  for (int c = 0; c < C; c += 8) {
    uint4 raw = *(const uint4*)(xp + c);
    unpack8(raw, x + c);
  }
  float s = 0.f, s2 = 0.f;
#pragma unroll
  for (int q = 0; q < C; q++) { s += x[q]; s2 = fmaf(x[q], x[q], s2); }
#pragma unroll
  for (int off = 32; off >= 1; off >>= 1) { s += __shfl_xor(s, off); s2 += __shfl_xor(s2, off); }
  const float mu = s / D;
  const float rs = rsqrtf(s2 / D - mu * mu + 1e-5f);
  const float* gp = g + lane * C;
  const float* bp = bta + lane * C;
#pragma unroll
  for (int c = 0; c < C; c += 8) {
    float4 g0 = *(const float4*)(gp + c), g1 = *(const float4*)(gp + c + 4);
    float4 t0 = *(const float4*)(bp + c), t1 = *(const float4*)(bp + c + 4);
    float y0 = fmaxf(fmaf((x[c + 0] - mu) * rs, g0.x, t0.x), 0.f);
    float y1 = fmaxf(fmaf((x[c + 1] - mu) * rs, g0.y, t0.y), 0.f);
    float y2 = fmaxf(fmaf((x[c + 2] - mu) * rs, g0.z, t0.z), 0.f);
    float y3 = fmaxf(fmaf((x[c + 3] - mu) * rs, g0.w, t0.w), 0.f);
    float y4 = fmaxf(fmaf((x[c + 4] - mu) * rs, g1.x, t1.x), 0.f);
    float y5 = fmaxf(fmaf((x[c + 5] - mu) * rs, g1.y, t1.y), 0.f);
    float y6 = fmaxf(fmaf((x[c + 6] - mu) * rs, g1.z, t1.z), 0.f);
    float y7 = fmaxf(fmaf((x[c + 7] - mu) * rs, g1.w, t1.w), 0.f);
    uint4 u;
    u.x = pack2(y0, y1); u.y = pack2(y2, y3);
    u.z = pack2(y4, y5); u.w = pack2(y6, y7);
    *(uint4*)(xp + c) = u;
  }
}

// ---- pair-XCD swizzle: bn-siblings (bid=2k,2k+1) land on the SAME XCD ----
// bijective for nwg % 16 == 0 (nwg=512 here)
static __device__ __forceinline__ int pair_swz(int bid, int nwg) {
  const int cpx2 = nwg >> 4;                 // pairs per XCD
  const int pr = bid >> 1, q = bid & 1;
  return (((pr & 7) * cpx2) + (pr >> 3)) * 2 + q;
}

// ---- 256x256 ring-4 pipelined bf16 GEMM, BK=32, distance-3 prefetch (R5-proven) ----
// MODE 0: A = plain bf16.  MODE 1: A = gathered pair rows from nodeFb.
template<int MODE>
__global__ __launch_bounds__(512)
void gemm256r(const unsigned short* __restrict__ A, int ldaE,
              const unsigned short* __restrict__ Bt, int ldbE,
              const float* __restrict__ bias,
              unsigned short* __restrict__ C, int ldcE, int ccol0,
              int NS, int NBN,
              const int* __restrict__ pidx,
              const unsigned short* __restrict__ nodeFb,
              const unsigned short* __restrict__ zsrc) {
  __shared__ __align__(16) unsigned char smem[131072];
  const int tid = threadIdx.x;
  const int lane = tid & 63, w = tid >> 6;
  const int swz = pair_swz(blockIdx.x, gridDim.x);
  const int bm = swz / NBN, bn = swz - bm * NBN;

  const int sslot = (tid & 3) ^ ((tid >> 3) & 3);
  const int srow = tid >> 2;
  const size_t ldaBy = (size_t)ldaE * 2, ldbBy = (size_t)ldbE * 2;
  const unsigned char* aG = (const unsigned char*)A + (size_t)(bm * 256 + srow) * ldaBy + sslot * 16;
  const unsigned char* bG = (const unsigned char*)Bt + (size_t)(bn * 256 + srow) * ldbBy + sslot * 16;

  const unsigned short* nbS[2];
  const unsigned short* nbO[2];
  if (MODE == 1) {
#pragma unroll
    for (int r = 0; r < 2; r++) {
      int pr = bm * 256 + r * 128 + srow;
      int2 so = *(const int2*)(pidx + 2 * pr);
      int b = pr >> 12;
      nbS[r] = nodeFb + (size_t)((b << 7) + so.x) * NODEF;
      nbO[r] = nodeFb + (size_t)((b << 7) + so.y) * NODEF;
    }
  }

  auto stage = [&](int s) {
    const int slot = s & 3;
    unsigned char* la = smem + slot * 16384 + w * 1024;
    unsigned char* lb = smem + 65536 + slot * 16384 + w * 1024;
    if (MODE == 0) {
      const unsigned char* sa = aG + (size_t)s * 64;
      async_copy16(sa, la);
      async_copy16(sa + 128 * ldaBy, la + 8192);
    } else {
      const int e = s * 32 + sslot * 8;
#pragma unroll
      for (int r = 0; r < 2; r++) {
        uintptr_t ps = (uintptr_t)(nbS[r] + e);
        uintptr_t po = (uintptr_t)(nbO[r] + (e - NODEF));
        uintptr_t pz = (uintptr_t)zsrc;
        uintptr_t sel = (e < NODEF) ? ps : ((e < KGEO) ? po : pz);
        async_copy16((const void*)sel, la + r * 8192);
      }
    }
    const unsigned char* sb = bG + (size_t)s * 64;
    async_copy16(sb, lb);
    async_copy16(sb + 128 * ldbBy, lb + 8192);
  };

  const int wm = w >> 2, wn = w & 3;
  const int frow = lane & 15;
  const int colb = (((lane >> 4) ^ ((frow >> 1) & 3)) << 4);
  const int aRowB = (wm * 128 + frow) * 64;
  const int bRowB = (wn * 64 + frow) * 64;

  f32x4 acc[8][4];
#pragma unroll
  for (int m = 0; m < 8; m++)
#pragma unroll
    for (int n = 0; n < 4; n++) acc[m][n] = (f32x4){0.f, 0.f, 0.f, 0.f};

  stage(0); stage(1); stage(2);
  for (int s = 0; s < NS; ++s) {
    if (s == NS - 1)      asm volatile("s_waitcnt vmcnt(0)" ::: "memory");
    else if (s == NS - 2) asm volatile("s_waitcnt vmcnt(4)" ::: "memory");
    else                  asm volatile("s_waitcnt vmcnt(8)" ::: "memory");
    __builtin_amdgcn_s_barrier();
    __builtin_amdgcn_sched_barrier(0);
    if (s + 3 < NS) stage(s + 3);
    const unsigned char* ab = smem + (s & 3) * 16384;
    const unsigned char* bb = smem + 65536 + (s & 3) * 16384;
    bf16x8 af[8], bfv[4];
#pragma unroll
    for (int m = 0; m < 8; m++) af[m] = *(const bf16x8*)(ab + aRowB + m * 1024 + colb);
#pragma unroll
    for (int n = 0; n < 4; n++) bfv[n] = *(const bf16x8*)(bb + bRowB + n * 1024 + colb);
    __builtin_amdgcn_s_setprio(1);
#pragma unroll
    for (int m = 0; m < 8; m++)
#pragma unroll
      for (int n = 0; n < 4; n++)
        acc[m][n] = __builtin_amdgcn_mfma_f32_16x16x32_bf16(af[m], bfv[n], acc[m][n], 0, 0, 0);
    __builtin_amdgcn_s_setprio(0);
    __builtin_amdgcn_sched_barrier(0);
  }
  const int rb = bm * 256 + wm * 128 + ((lane >> 4) << 2);
  const int cb = bn * 256 + wn * 64 + frow;
#pragma unroll
  for (int n = 0; n < 4; n++) {
    const int col = cb + n * 16;
    const float bv = bias[col];
#pragma unroll
    for (int m = 0; m < 8; m++)
#pragma unroll
      for (int i = 0; i < 4; i++) {
        const int row = rb + m * 16 + i;
        C[(size_t)row * ldcE + ccol0 + col] = f2b(acc[m][n][i] + bv);
      }
  }
}

// ---- 256x256 ring-4 GEMM with A staged from f32 + relu + cvt (fused relu_cast) ----
// A f32 [M][1024]. Per stage per thread: 4x global_load_dwordx4 (f32, to regs)
// + 2x global_load_lds (B) = 6 vmcnt events, issued at distance 2.
// Head of phase s: outstanding = stages {s, s+1} = 12 -> vmcnt(6) drains stage s
// (s = NS-1: only 6 outstanding -> vmcnt(0)). A regs: 2 static sets, x2 unroll.
// ds_write of A slot s&3 at head of phase s: last readers finished phase s-4. Safe.
__global__ __launch_bounds__(512)
void gemm256f(const float* __restrict__ A,            // f32, lda = 1024
              const unsigned short* __restrict__ Bt,  // [512][1024] bf16
              const float* __restrict__ bias,
              unsigned short* __restrict__ C, int ldcE, int ccol0,
              int NBN) {
  constexpr int NS = 32;                               // K=1024 / BK=32
  __shared__ __align__(16) unsigned char smem[131072];
  const int tid = threadIdx.x;
  const int lane = tid & 63, w = tid >> 6;
  const int swz = pair_swz(blockIdx.x, gridDim.x);
  const int bm = swz / NBN, bn = swz - bm * NBN;

  const int sslot = (tid & 3) ^ ((tid >> 3) & 3);      // source k-slot (pre-swizzle)
  const int srow = tid >> 2;
  const float* aG = A + (size_t)(bm * 256 + srow) * 1024 + sslot * 8;
  const unsigned char* bG = (const unsigned char*)Bt + (size_t)(bn * 256 + srow) * 2048 + sslot * 16;
  unsigned char* laBase = smem + (srow * 64) + (tid & 3) * 16;
  unsigned char* lbBase = smem + 65536 + w * 1024;

  uint4 ra0[4], ra1[4];                                // 2 static reg sets

  auto issueA = [&](int s, uint4* ra) {
    const float* p0 = aG + (size_t)s * 32;
    ra[0] = *(const uint4*)(p0);
    ra[1] = *(const uint4*)(p0 + 4);
    ra[2] = *(const uint4*)(p0 + 128 * 1024);
    ra[3] = *(const uint4*)(p0 + 128 * 1024 + 4);
  };
  auto issueB = [&](int s) {
    const int slot = s & 3;
    const unsigned char* sb = bG + (size_t)s * 64;
    async_copy16(sb, lbBase + slot * 16384);
    async_copy16(sb + 128 * 2048, lbBase + slot * 16384 + 8192);
  };
  auto writeA = [&](int s, const uint4* ra) {
    const int slot = s & 3;
#pragma unroll
    for (int r = 0; r < 2; r++) {
      float x0 = fmaxf(__uint_as_float(ra[2 * r].x), 0.f);
      float x1 = fmaxf(__uint_as_float(ra[2 * r].y), 0.f);
      float x2 = fmaxf(__uint_as_float(ra[2 * r].z), 0.f);
      float x3 = fmaxf(__uint_as_float(ra[2 * r].w), 0.f);
      float x4 = fmaxf(__uint_as_float(ra[2 * r + 1].x), 0.f);
      float x5 = fmaxf(__uint_as_float(ra[2 * r + 1].y), 0.f);
      float x6 = fmaxf(__uint_as_float(ra[2 * r + 1].z), 0.f);
      float x7 = fmaxf(__uint_as_float(ra[2 * r + 1].w), 0.f);
      uint4 u;
      u.x = pack2(x0, x1); u.y = pack2(x2, x3);
      u.z = pack2(x4, x5); u.w = pack2(x6, x7);
      *(uint4*)(laBase + slot * 16384 + r * 8192) = u;
    }
  };

  const int wm = w >> 2, wn = w & 3;
  const int frow = lane & 15;
  const int colb = (((lane >> 4) ^ ((frow >> 1) & 3)) << 4);
  const int aRowB = (wm * 128 + frow) * 64;
  const int bRowB = (wn * 64 + frow) * 64;

  f32x4 acc[8][4];
#pragma unroll
  for (int m = 0; m < 8; m++)
#pragma unroll
    for (int n = 0; n < 4; n++) acc[m][n] = (f32x4){0.f, 0.f, 0.f, 0.f};

  // prologue: stages 0 (set0) and 1 (set1)
  issueA(0, ra0); issueB(0);
  issueA(1, ra1); issueB(1);

#pragma unroll 1
  for (int s = 0; s < NS; s += 2) {
#pragma unroll
    for (int half = 0; half < 2; half++) {
      const int sc = s + half;
      uint4* raC = half ? ra1 : ra0;
      if (sc == NS - 1) asm volatile("s_waitcnt vmcnt(0)" ::: "memory");
      else              asm volatile("s_waitcnt vmcnt(6)" ::: "memory");
      __builtin_amdgcn_sched_barrier(0);
      writeA(sc, raC);                       // slot sc&3: readers done at sc-4
      if (sc + 2 < NS) { issueA(sc + 2, raC); issueB(sc + 2); }
      asm volatile("s_waitcnt lgkmcnt(0)" ::: "memory");
      __builtin_amdgcn_s_barrier();
      __builtin_amdgcn_sched_barrier(0);
      const unsigned char* ab = smem + (sc & 3) * 16384;
      const unsigned char* bb = smem + 65536 + (sc & 3) * 16384;
      bf16x8 af[8], bfv[4];
#pragma unroll
      for (int m = 0; m < 8; m++) af[m] = *(const bf16x8*)(ab + aRowB + m * 1024 + colb);
#pragma unroll
      for (int n = 0; n < 4; n++) bfv[n] = *(const bf16x8*)(bb + bRowB + n * 1024 + colb);
      __builtin_amdgcn_s_setprio(1);
#pragma unroll
      for (int m = 0; m < 8; m++)
#pragma unroll
        for (int n = 0; n < 4; n++)
          acc[m][n] = __builtin_amdgcn_mfma_f32_16x16x32_bf16(af[m], bfv[n], acc[m][n], 0, 0, 0);
      __builtin_amdgcn_s_setprio(0);
      __builtin_amdgcn_sched_barrier(0);
      __builtin_amdgcn_s_barrier();          // keep skew <=1 phase before next writeA
    }
  }
  const int rb = bm * 256 + wm * 128 + ((lane >> 4) << 2);
  const int cb = bn * 256 + wn * 64 + frow;
#pragma unroll
  for (int n = 0; n < 4; n++) {
    const int col = cb + n * 16;
    const float bv = bias[col];
#pragma unroll
    for (int m = 0; m < 8; m++)
#pragma unroll
      for (int i = 0; i < 4; i++) {
        const int row = rb + m * 16 + i;
        C[(size_t)row * ldcE + ccol0 + col] = f2b(acc[m][n][i] + bv);
      }
  }
}

// ---- 128x128 m97-structure GEMM for cls layer (N=50) + fused score scatter ----
__global__ __launch_bounds__(256)
void gemm_cls(const unsigned short* __restrict__ A, int lda,
              const unsigned short* __restrict__ Bt,
              const float* __restrict__ bias,
              float* __restrict__ C,
              int Ktot,
              const int* __restrict__ pidx,
              unsigned long long* __restrict__ scat) {
  __shared__ unsigned short ldsA[128 * 64];
  __shared__ unsigned short ldsB[128 * 64];
  const int tid = threadIdx.x;
  const int lane = tid & 63, wid = tid >> 6;
  const int cpx = gridDim.x >> 3;
  const int bm = (blockIdx.x & 7) * cpx + (blockIdx.x >> 3);

  const int srow = wid * 32 + (lane >> 3);
  const int skof = (lane & 7) * 8;
  const unsigned short* ag = A + (size_t)(bm * 128 + srow) * lda + skof;
  const unsigned short* bg = Bt + (size_t)srow * Ktot + skof;

  f32x4 acc[4][4];
#pragma unroll
  for (int m = 0; m < 4; m++)
#pragma unroll
    for (int n = 0; n < 4; n++) acc[m][n] = (f32x4){0.f, 0.f, 0.f, 0.f};

  const int wm = wid >> 1, wn = wid & 1;
  const int frow = lane & 15;
  const int kgrp = (lane >> 4) << 3;

  for (int kt = 0; kt < Ktot; kt += 64) {
#pragma unroll
    for (int i = 0; i < 4; i++) {
      async_copy16(ag + (size_t)i * 8 * lda + kt, &ldsA[wid * 2048 + i * 512]);
      async_copy16(bg + (size_t)i * 8 * Ktot + kt, &ldsB[wid * 2048 + i * 512]);
    }
    __syncthreads();
#pragma unroll
    for (int kk = 0; kk < 64; kk += 32) {
      bf16x8 af[4], bfr[4];
#pragma unroll
      for (int m = 0; m < 4; m++)
        af[m] = *(const bf16x8*)&ldsA[(wm * 64 + m * 16 + frow) * 64 + kk + kgrp];
#pragma unroll
      for (int n = 0; n < 4; n++)
        bfr[n] = *(const bf16x8*)&ldsB[(wn * 64 + n * 16 + frow) * 64 + kk + kgrp];
#pragma unroll
      for (int m = 0; m < 4; m++)
#pragma unroll
        for (int n = 0; n < 4; n++)
          acc[m][n] = __builtin_amdgcn_mfma_f32_16x16x32_bf16(af[m], bfr[n], acc[m][n], 0, 0, 0);
    }
    __syncthreads();
  }
  const int rb = bm * 128 + wm * 64 + ((lane >> 4) << 2);
#pragma unroll
  for (int n = 0; n < 4; n++) {
    const int col = wn * 64 + frow + n * 16;
    const float bv = (col < OUTC) ? bias[col] : 0.f;
#pragma unroll
    for (int m = 0; m < 4; m++)
#pragma unroll
      for (int i = 0; i < 4; i++) {
        const int row = rb + m * 16 + i;
        if (col < OUTC) C[(size_t)row * OUTC + col] = acc[m][n][i] + bv;
      }
  }
  // fused score: wn==0 waves hold cols 0..63 of their 64 rows
  if (wn == 0) {
#pragma unroll
    for (int m = 0; m < 4; m++)
#pragma unroll
      for (int i = 0; i < 4; i++) {
        float mx = -1e30f;
#pragma unroll
        for (int n = 0; n < 4; n++) {
          const int col = n * 16 + frow;
          float v = acc[m][n][i] + ((col < OUTC) ? bias[col] : 0.f);
          if (col < OUTC) mx = fmaxf(mx, v);
        }
        mx = fmaxf(mx, __shfl_xor(mx, 1));
        mx = fmaxf(mx, __shfl_xor(mx, 2));
        mx = fmaxf(mx, __shfl_xor(mx, 4));
        mx = fmaxf(mx, __shfl_xor(mx, 8));
        if (frow == 0) {
          const int row = rb + m * 16 + i;
          float sc = 1.f / (1.f + expf(-mx));
          int b = row >> 12, p = row & 4095;
          int s = pidx[2 * row], o = pidx[2 * row + 1];
          unsigned long long key = (((unsigned long long)(p + 1)) << 32) |
                                   (unsigned long long)__float_as_uint(sc);
          atomicMax(&scat[((size_t)(b * N_ + s) << 7) + o], key);
        }
      }
  }
}

__global__ void relmat_kernel(const unsigned long long* __restrict__ scat, float* __restrict__ out) {
  int i = blockIdx.x * blockDim.x + threadIdx.x;
  if (i >= B_ * N_ * N_) return;
  unsigned long long v = scat[i];
  out[i] = v ? __uint_as_float((unsigned)(v & 0xffffffffu)) : 0.f;
}

extern "C" void kernel_launch(void* const* d_in, const int* in_sizes, int n_in,
                              void* d_out, int out_size, void* d_ws, size_t ws_size,
                              hipStream_t stream) {
  const float* visual_feat = (const float*)d_in[0];
  const float* box_info    = (const float*)d_in[1];
  const float* pred_logits = (const float*)d_in[2];
  const int*   pair_idx    = (const int*)d_in[3];
  const float* obj_sem_w   = (const float*)d_in[4];
  const float* pos_w1 = (const float*)d_in[5];
  const float* pos_b1 = (const float*)d_in[6];
  const float* pos_w2 = (const float*)d_in[7];
  const float* pos_b2 = (const float*)d_in[8];
  const float* vis_w  = (const float*)d_in[9];
  const float* vis_b  = (const float*)d_in[10];
  const float* geo_w  = (const float*)d_in[11];
  const float* geo_b  = (const float*)d_in[12];
  const float* fus_g  = (const float*)d_in[13];
  const float* fus_bt = (const float*)d_in[14];
  const float* fus_w  = (const float*)d_in[15];
  const float* fus_b  = (const float*)d_in[16];
  const float* cls_g  = (const float*)d_in[17];
  const float* cls_bt = (const float*)d_in[18];
  const float* cls_w  = (const float*)d_in[19];
  const float* cls_b  = (const float*)d_in[20];

  char* ws = (char*)d_ws;
  size_t off = 0;
  auto alloc = [&](size_t bytes) { char* p = ws + off; off += (bytes + 255) & ~(size_t)255; return p; };
  unsigned short* fused = (unsigned short*)alloc((size_t)M_ * 1024 * 2);      // 134 MB
  unsigned short* fused2 = (unsigned short*)alloc((size_t)M_ * 512 * 2);      // 67 MB
  unsigned short* nodeFb = (unsigned short*)alloc((size_t)B_ * N_ * NODEF * 2);
  unsigned short* wT_vis = (unsigned short*)alloc((size_t)512 * 1024 * 2);
  unsigned short* wT_geo = (unsigned short*)alloc((size_t)512 * KGEOP * 2);
  unsigned short* wT_fus = (unsigned short*)alloc((size_t)512 * 1024 * 2);
  unsigned short* wT_cls = (unsigned short*)alloc((size_t)128 * 512 * 2);
  unsigned long long* scat = (unsigned long long*)alloc((size_t)B_ * N_ * N_ * 8);

  float* out_logits = (float*)d_out;
  float* out_rel = out_logits + (size_t)M_ * OUTC;

  prep_kernel<<<dim3((PREP_TOT + 255) / 256), 256, 0, stream>>>(
      (uint4*)scat, vis_w, wT_vis, geo_w, wT_geo, fus_w, wT_fus, cls_w, wT_cls);
  node_kernel<<<dim3(B_ * N_), 128, 0, stream>>>(box_info, pred_logits, obj_sem_w,
                                                 pos_w1, pos_b1, pos_w2, pos_b2, nodeFb);
  // geo GEMM with fused pair-gather (A from nodeFb via per-lane gload_lds src)
  gemm256r<1><<<dim3(512), 512, 0, stream>>>(nullptr, 0, wT_geo, KGEOP, geo_b,
                                             fused, 1024, 512, KGEOP / 32, 2,
                                             pair_idx, nodeFb, (const unsigned short*)scat);
  gemm256f<<<dim3(512), 512, 0, stream>>>(visual_feat, wT_vis, vis_b,
                                          fused, 1024, 0, 2);
  ln_relu_kernel<1024><<<dim3(M_ / 4), 256, 0, stream>>>(fused, fus_g, fus_bt);
  gemm256r<0><<<dim3(512), 512, 0, stream>>>(fused, 1024, wT_fus, 1024, fus_b,
                                             fused2, 512, 0, 1024 / 32, 2,
                                             nullptr, nullptr, nullptr);
  ln_relu_kernel<512><<<dim3(M_ / 4), 256, 0, stream>>>(fused2, cls_g, cls_bt);
  gemm_cls<<<dim3(512), 256, 0, stream>>>(fused2, 512, wT_cls, cls_b,
                                          out_logits, 512, pair_idx, scat);
  relmat_kernel<<<dim3((B_ * N_ * N_) / 256), 256, 0, stream>>>(scat, out_rel);
}

// Round 15
// 429.586 us; speedup vs baseline: 1.1781x; 1.0333x over previous
//
#include <hip/hip_runtime.h>
#include <cstdint>

#define B_    16
#define N_    128
#define P_    4096
#define M_    65536     // B_*P_
#define DIN   1024
#define DHID  512
#define DGEO  128
#define DEMB  200
#define NODEF 328       // DGEO + DEMB
#define NOBJ  151
#define OUTC  50
#define KGEO  656
#define KGEOP 672       // geo K padded to multiple of 32 (ring BK=32)

typedef __attribute__((ext_vector_type(8))) short bf16x8;
typedef __attribute__((ext_vector_type(4))) float f32x4;

typedef __attribute__((address_space(3))) unsigned char lds_u8;
typedef __attribute__((address_space(1))) unsigned char glb_u8;

static __device__ __forceinline__ void async_copy16(const void* g, void* l) {
  __builtin_amdgcn_global_load_lds((const glb_u8*)g, (lds_u8*)l, 16, 0, 0);
}

static __device__ __forceinline__ unsigned short f2b(float f) {
  union { float f; unsigned u; } v; v.f = f;
  unsigned r = v.u + 0x7fffu + ((v.u >> 16) & 1u);
  return (unsigned short)(r >> 16);
}
static __device__ __forceinline__ float b2f(unsigned short b) {
  union { unsigned u; float f; } v; v.u = ((unsigned)b) << 16;
  return v.f;
}
static __device__ __forceinline__ unsigned pack2(float a, float b) {
  return (unsigned)f2b(a) | ((unsigned)f2b(b) << 16);
}
static __device__ __forceinline__ void unpack8(uint4 raw, float* x) {
  x[0] = b2f(raw.x & 0xffffu); x[1] = b2f(raw.x >> 16);
  x[2] = b2f(raw.y & 0xffffu); x[3] = b2f(raw.y >> 16);
  x[4] = b2f(raw.z & 0xffffu); x[5] = b2f(raw.z >> 16);
  x[6] = b2f(raw.w & 0xffffu); x[7] = b2f(raw.w >> 16);
}

// ---- merged prologue: zero scat + all 4 weight transposes in one launch ----
#define ZN   131072                    // scat zero, uint4 count (2 MB)
#define TV   (512 * 1024)              // wT_vis elems
#define TG   (512 * KGEOP)             // wT_geo elems
#define TF   (512 * 1024)              // wT_fus elems
#define TC   (128 * 512)               // wT_cls elems
#define PREP_TOT (ZN + TV + TG + TF + TC)
__global__ __launch_bounds__(256)
void prep_kernel(uint4* __restrict__ scat,
                 const float* __restrict__ vis_w, unsigned short* __restrict__ wT_vis,
                 const float* __restrict__ geo_w, unsigned short* __restrict__ wT_geo,
                 const float* __restrict__ fus_w, unsigned short* __restrict__ wT_fus,
                 const float* __restrict__ cls_w, unsigned short* __restrict__ wT_cls) {
  int idx = blockIdx.x * 256 + threadIdx.x;
  if (idx < ZN) { scat[idx] = make_uint4(0, 0, 0, 0); return; }
  idx -= ZN;
  if (idx < TV) {
    int n = idx >> 10, k = idx & 1023;
    wT_vis[idx] = f2b(vis_w[(size_t)k * 512 + n]);
    return;
  }
  idx -= TV;
  if (idx < TG) {
    int n = idx / KGEOP, k = idx - n * KGEOP;
    wT_geo[idx] = (k < KGEO) ? f2b(geo_w[(size_t)k * 512 + n]) : 0;
    return;
  }
  idx -= TG;
  if (idx < TF) {
    int n = idx >> 10, k = idx & 1023;
    wT_fus[idx] = f2b(fus_w[(size_t)k * 512 + n]);
    return;
  }
  idx -= TF;
  if (idx < TC) {
    int n = idx >> 9, k = idx & 511;
    wT_cls[idx] = (n < OUTC) ? f2b(cls_w[(size_t)k * OUTC + n]) : 0;
  }
}

// ---- per-node features (relu'd, bf16): nodeFb[node] = [relu(pos)(128), relu(sem)(200)] ----
__global__ __launch_bounds__(128)
void node_kernel(const float* __restrict__ box, const float* __restrict__ plog,
                 const float* __restrict__ semw,
                 const float* __restrict__ w1, const float* __restrict__ b1,
                 const float* __restrict__ w2, const float* __restrict__ b2,
                 unsigned short* __restrict__ nodeFb) {
  const int node = blockIdx.x;
  const int t = threadIdx.x;
  __shared__ float sBox[9];
  __shared__ float sH[128];
  __shared__ float sE[NOBJ];
  __shared__ float sRed[4];
  if (t < 9) sBox[t] = box[node * 9 + t];
  float l0 = (t < NOBJ) ? plog[node * NOBJ + t] : -1e30f;
  float l1 = (t + 128 < NOBJ) ? plog[node * NOBJ + t + 128] : -1e30f;
  __syncthreads();
  float h = b1[t];
#pragma unroll
  for (int i = 0; i < 9; i++) h = fmaf(sBox[i], w1[i * 128 + t], h);
  h = fmaxf(h, 0.f);
  sH[t] = h;
  float mx = fmaxf(l0, l1);
#pragma unroll
  for (int off = 32; off >= 1; off >>= 1) mx = fmaxf(mx, __shfl_xor(mx, off));
  if ((t & 63) == 0) sRed[t >> 6] = mx;
  __syncthreads();
  mx = fmaxf(sRed[0], sRed[1]);
  float e0 = (t < NOBJ) ? expf(l0 - mx) : 0.f;
  float e1 = (t + 128 < NOBJ) ? expf(l1 - mx) : 0.f;
  if (t < NOBJ) sE[t] = e0;
  if (t + 128 < NOBJ) sE[t + 128] = e1;
  float sm = e0 + e1;
#pragma unroll
  for (int off = 32; off >= 1; off >>= 1) sm += __shfl_xor(sm, off);
  if ((t & 63) == 0) sRed[2 + (t >> 6)] = sm;
  __syncthreads();
  const float inv = 1.f / (sRed[2] + sRed[3]);
  float pv = b2[t];
  for (int i = 0; i < 128; i++) pv = fmaf(sH[i], w2[i * 128 + t], pv);
  nodeFb[(size_t)node * NODEF + t] = f2b(fmaxf(pv, 0.f));
  float a0 = 0.f, a1 = 0.f;
  const int d1 = (t + 128 < DEMB) ? (t + 128) : 0;
  for (int i = 0; i < NOBJ; i++) {
    float e = sE[i];
    a0 = fmaf(e, semw[i * DEMB + t], a0);
    a1 = fmaf(e, semw[i * DEMB + d1], a1);
  }
  nodeFb[(size_t)node * NODEF + 128 + t] = f2b(fmaxf(a0 * inv, 0.f));
  if (t + 128 < DEMB) nodeFb[(size_t)node * NODEF + 128 + t + 128] = f2b(fmaxf(a1 * inv, 0.f));
}

// ---- fused LayerNorm + ReLU, in place, wave per row ----
template<int D>
__global__ __launch_bounds__(256)
void ln_relu_kernel(unsigned short* __restrict__ X,
                    const float* __restrict__ g, const float* __restrict__ bta) {
  constexpr int C = D / 64;
  const int lane = threadIdx.x & 63, wv = threadIdx.x >> 6;
  const size_t row = (size_t)blockIdx.x * 4 + wv;
  unsigned short* xp = X + row * D + lane * C;
  float x[C];
#pragma unroll
  for (int c = 0; c < C; c += 8) {
    uint4 raw = *(const uint4*)(xp + c);
    unpack8(raw, x + c);
  }
  float s = 0.f, s2 = 0.f;
#pragma unroll
  for (int q = 0; q < C; q++) { s += x[q]; s2 = fmaf(x[q], x[q], s2); }
#pragma unroll
  for (int off = 32; off >= 1; off >>= 1) { s += __shfl_xor(s, off); s2 += __shfl_xor(s2, off); }
  const float mu = s / D;
  const float rs = rsqrtf(s2 / D - mu * mu + 1e-5f);
  const float* gp = g + lane * C;
  const float* bp = bta + lane * C;
#pragma unroll
  for (int c = 0; c < C; c += 8) {
    float4 g0 = *(const float4*)(gp + c), g1 = *(const float4*)(gp + c + 4);
    float4 t0 = *(const float4*)(bp + c), t1 = *(const float4*)(bp + c + 4);
    float y0 = fmaxf(fmaf((x[c + 0] - mu) * rs, g0.x, t0.x), 0.f);
    float y1 = fmaxf(fmaf((x[c + 1] - mu) * rs, g0.y, t0.y), 0.f);
    float y2 = fmaxf(fmaf((x[c + 2] - mu) * rs, g0.z, t0.z), 0.f);
    float y3 = fmaxf(fmaf((x[c + 3] - mu) * rs, g0.w, t0.w), 0.f);
    float y4 = fmaxf(fmaf((x[c + 4] - mu) * rs, g1.x, t1.x), 0.f);
    float y5 = fmaxf(fmaf((x[c + 5] - mu) * rs, g1.y, t1.y), 0.f);
    float y6 = fmaxf(fmaf((x[c + 6] - mu) * rs, g1.z, t1.z), 0.f);
    float y7 = fmaxf(fmaf((x[c + 7] - mu) * rs, g1.w, t1.w), 0.f);
    uint4 u;
    u.x = pack2(y0, y1); u.y = pack2(y2, y3);
    u.z = pack2(y4, y5); u.w = pack2(y6, y7);
    *(uint4*)(xp + c) = u;
  }
}

// ---- pair-XCD swizzle: bn-siblings (bid=2k,2k+1) land on the SAME XCD ----
// bijective for nwg % 16 == 0
static __device__ __forceinline__ int pair_swz(int bid, int nwg) {
  const int cpx2 = nwg >> 4;                 // pairs per XCD
  const int pr = bid >> 1, q = bid & 1;
  return (((pr & 7) * cpx2) + (pr >> 3)) * 2 + q;
}

// ---- 256x256 ring-4 pipelined bf16 GEMM, BK=32, distance-3 prefetch (R5-proven) ----
// MODE 0: A = plain bf16.  MODE 1: A = gathered pair rows from nodeFb.
template<int MODE>
__global__ __launch_bounds__(512)
void gemm256r(const unsigned short* __restrict__ A, int ldaE,
              const unsigned short* __restrict__ Bt, int ldbE,
              const float* __restrict__ bias,
              unsigned short* __restrict__ C, int ldcE, int ccol0,
              int NS, int NBN,
              const int* __restrict__ pidx,
              const unsigned short* __restrict__ nodeFb,
              const unsigned short* __restrict__ zsrc) {
  __shared__ __align__(16) unsigned char smem[131072];
  const int tid = threadIdx.x;
  const int lane = tid & 63, w = tid >> 6;
  const int swz = pair_swz(blockIdx.x, gridDim.x);
  const int bm = swz / NBN, bn = swz - bm * NBN;

  const int sslot = (tid & 3) ^ ((tid >> 3) & 3);
  const int srow = tid >> 2;
  const size_t ldaBy = (size_t)ldaE * 2, ldbBy = (size_t)ldbE * 2;
  const unsigned char* aG = (const unsigned char*)A + (size_t)(bm * 256 + srow) * ldaBy + sslot * 16;
  const unsigned char* bG = (const unsigned char*)Bt + (size_t)(bn * 256 + srow) * ldbBy + sslot * 16;

  const unsigned short* nbS[2];
  const unsigned short* nbO[2];
  if (MODE == 1) {
#pragma unroll
    for (int r = 0; r < 2; r++) {
      int pr = bm * 256 + r * 128 + srow;
      int2 so = *(const int2*)(pidx + 2 * pr);
      int b = pr >> 12;
      nbS[r] = nodeFb + (size_t)((b << 7) + so.x) * NODEF;
      nbO[r] = nodeFb + (size_t)((b << 7) + so.y) * NODEF;
    }
  }

  auto stage = [&](int s) {
    const int slot = s & 3;
    unsigned char* la = smem + slot * 16384 + w * 1024;
    unsigned char* lb = smem + 65536 + slot * 16384 + w * 1024;
    if (MODE == 0) {
      const unsigned char* sa = aG + (size_t)s * 64;
      async_copy16(sa, la);
      async_copy16(sa + 128 * ldaBy, la + 8192);
    } else {
      const int e = s * 32 + sslot * 8;
#pragma unroll
      for (int r = 0; r < 2; r++) {
        uintptr_t ps = (uintptr_t)(nbS[r] + e);
        uintptr_t po = (uintptr_t)(nbO[r] + (e - NODEF));
        uintptr_t pz = (uintptr_t)zsrc;
        uintptr_t sel = (e < NODEF) ? ps : ((e < KGEO) ? po : pz);
        async_copy16((const void*)sel, la + r * 8192);
      }
    }
    const unsigned char* sb = bG + (size_t)s * 64;
    async_copy16(sb, lb);
    async_copy16(sb + 128 * ldbBy, lb + 8192);
  };

  const int wm = w >> 2, wn = w & 3;
  const int frow = lane & 15;
  const int colb = (((lane >> 4) ^ ((frow >> 1) & 3)) << 4);
  const int aRowB = (wm * 128 + frow) * 64;
  const int bRowB = (wn * 64 + frow) * 64;

  f32x4 acc[8][4];
#pragma unroll
  for (int m = 0; m < 8; m++)
#pragma unroll
    for (int n = 0; n < 4; n++) acc[m][n] = (f32x4){0.f, 0.f, 0.f, 0.f};

  stage(0); stage(1); stage(2);
  for (int s = 0; s < NS; ++s) {
    if (s == NS - 1)      asm volatile("s_waitcnt vmcnt(0)" ::: "memory");
    else if (s == NS - 2) asm volatile("s_waitcnt vmcnt(4)" ::: "memory");
    else                  asm volatile("s_waitcnt vmcnt(8)" ::: "memory");
    __builtin_amdgcn_s_barrier();
    __builtin_amdgcn_sched_barrier(0);
    if (s + 3 < NS) stage(s + 3);
    const unsigned char* ab = smem + (s & 3) * 16384;
    const unsigned char* bb = smem + 65536 + (s & 3) * 16384;
    bf16x8 af[8], bfv[4];
#pragma unroll
    for (int m = 0; m < 8; m++) af[m] = *(const bf16x8*)(ab + aRowB + m * 1024 + colb);
#pragma unroll
    for (int n = 0; n < 4; n++) bfv[n] = *(const bf16x8*)(bb + bRowB + n * 1024 + colb);
    __builtin_amdgcn_s_setprio(1);
#pragma unroll
    for (int m = 0; m < 8; m++)
#pragma unroll
      for (int n = 0; n < 4; n++)
        acc[m][n] = __builtin_amdgcn_mfma_f32_16x16x32_bf16(af[m], bfv[n], acc[m][n], 0, 0, 0);
    __builtin_amdgcn_s_setprio(0);
    __builtin_amdgcn_sched_barrier(0);
  }
  const int rb = bm * 256 + wm * 128 + ((lane >> 4) << 2);
  const int cb = bn * 256 + wn * 64 + frow;
#pragma unroll
  for (int n = 0; n < 4; n++) {
    const int col = cb + n * 16;
    const float bv = bias[col];
#pragma unroll
    for (int m = 0; m < 8; m++)
#pragma unroll
      for (int i = 0; i < 4; i++) {
        const int row = rb + m * 16 + i;
        C[(size_t)row * ldcE + ccol0 + col] = f2b(acc[m][n][i] + bv);
      }
  }
}

// ---- 128x256 ring-2 GEMM, A f32+relu+cvt reg-staged, HALVED acc for 2 blocks/CU ----
// 512 thr (8 waves, 2M x 4N), each wave 64x64 -> acc[4][4] = 64 AGPR.
// LDS = A 2x8K + B 2x16K = 48 KB; launch_bounds(512,4) targets <=128 regs
// -> 4 waves/SIMD = 2 INDEPENDENT blocks/CU (m114 overlap absorbs barrier stalls).
// Per stage per thread: 2x A f32 uint4 loads (regs) + 2x B gload_lds = 4 vm events.
// Ledger (oldest-first; A(s) issued head of s-2, B(s) issued END of s-2):
//   head of phase s: queue = A(s),B(s),A(s+1),B(s+1) -> vmcnt(4) drains stage s;
//   s==NS-1: nothing newer -> vmcnt(0) (R3 bug class).
// writeA(s) -> slot s&1 (readers finished phase s-2, all waves past barrier-2 of s-1);
// issueB(s+2) AFTER barrier-2 (overwrites B slot s&1 whose readers just finished).
__global__ __launch_bounds__(512, 4)
void gemm256f3(const float* __restrict__ A,            // f32, lda = 1024
               const unsigned short* __restrict__ Bt,  // [512][1024] bf16
               const float* __restrict__ bias,
               unsigned short* __restrict__ C, int ldcE, int ccol0,
               int NBN) {
  constexpr int NS = 32;                               // K=1024 / BK=32
  __shared__ __align__(16) unsigned char smem[49152];  // A 2x8K | B 2x16K @16K
  const int tid = threadIdx.x;
  const int lane = tid & 63, w = tid >> 6;
  const int swz = pair_swz(blockIdx.x, gridDim.x);
  const int bm = swz / NBN, bn = swz - bm * NBN;       // bm 0..511, bn 0..1

  const int sslot = (tid & 3) ^ ((tid >> 3) & 3);      // source k-slot (pre-swizzle)
  const int srow = tid >> 2;                           // 0..127
  const float* aG = A + (size_t)(bm * 128 + srow) * 1024 + sslot * 8;
  const unsigned char* bG = (const unsigned char*)Bt + (size_t)(bn * 256 + srow) * 2048 + sslot * 16;
  unsigned char* laBase = smem + srow * 64 + (tid & 3) * 16;
  unsigned char* lbBase = smem + 16384 + w * 1024;

  uint4 ra0[2], ra1[2];                                // 2 static reg sets

  auto issueA = [&](int s, uint4* ra) {
    const float* p0 = aG + (size_t)s * 32;
    ra[0] = *(const uint4*)(p0);
    ra[1] = *(const uint4*)(p0 + 4);
  };
  auto issueB = [&](int s) {
    const int slot = s & 1;
    const unsigned char* sb = bG + (size_t)s * 64;
    async_copy16(sb, lbBase + slot * 16384);
    async_copy16(sb + 128 * 2048, lbBase + slot * 16384 + 8192);
  };
  auto writeA = [&](int s, const uint4* ra) {
    const int slot = s & 1;
    float x0 = fmaxf(__uint_as_float(ra[0].x), 0.f);
    float x1 = fmaxf(__uint_as_float(ra[0].y), 0.f);
    float x2 = fmaxf(__uint_as_float(ra[0].z), 0.f);
    float x3 = fmaxf(__uint_as_float(ra[0].w), 0.f);
    float x4 = fmaxf(__uint_as_float(ra[1].x), 0.f);
    float x5 = fmaxf(__uint_as_float(ra[1].y), 0.f);
    float x6 = fmaxf(__uint_as_float(ra[1].z), 0.f);
    float x7 = fmaxf(__uint_as_float(ra[1].w), 0.f);
    uint4 u;
    u.x = pack2(x0, x1); u.y = pack2(x2, x3);
    u.z = pack2(x4, x5); u.w = pack2(x6, x7);
    *(uint4*)(laBase + slot * 8192) = u;
  };

  const int wm = w >> 2, wn = w & 3;                   // 2M x 4N waves, 64x64 each
  const int frow = lane & 15;
  const int colb = (((lane >> 4) ^ ((frow >> 1) & 3)) << 4);
  const int aRowB = (wm * 64 + frow) * 64;
  const int bRowB = (wn * 64 + frow) * 64;

  f32x4 acc[4][4];
#pragma unroll
  for (int m = 0; m < 4; m++)
#pragma unroll
    for (int n = 0; n < 4; n++) acc[m][n] = (f32x4){0.f, 0.f, 0.f, 0.f};

  issueA(0, ra0); issueB(0);
  issueA(1, ra1); issueB(1);

#pragma unroll 1
  for (int s = 0; s < NS; s += 2) {
#pragma unroll
    for (int half = 0; half < 2; half++) {
      const int sc = s + half;
      uint4* raC = half ? ra1 : ra0;
      if (sc == NS - 1) asm volatile("s_waitcnt vmcnt(0)" ::: "memory");
      else              asm volatile("s_waitcnt vmcnt(4)" ::: "memory");
      __builtin_amdgcn_sched_barrier(0);
      writeA(sc, raC);                       // slot sc&1: readers done at sc-2
      if (sc + 2 < NS) issueA(sc + 2, raC);  // regs only — safe before barrier
      asm volatile("s_waitcnt lgkmcnt(0)" ::: "memory");
      __builtin_amdgcn_s_barrier();
      __builtin_amdgcn_sched_barrier(0);
      const unsigned char* ab = smem + (sc & 1) * 8192;
      const unsigned char* bb = smem + 16384 + (sc & 1) * 16384;
      bf16x8 af[4];
#pragma unroll
      for (int m = 0; m < 4; m++) af[m] = *(const bf16x8*)(ab + aRowB + m * 1024 + colb);
      __builtin_amdgcn_s_setprio(1);
#pragma unroll
      for (int n = 0; n < 4; n++) {
        bf16x8 bf = *(const bf16x8*)(bb + bRowB + n * 1024 + colb);
#pragma unroll
        for (int m = 0; m < 4; m++)
          acc[m][n] = __builtin_amdgcn_mfma_f32_16x16x32_bf16(af[m], bf, acc[m][n], 0, 0, 0);
      }
      __builtin_amdgcn_s_setprio(0);
      __builtin_amdgcn_sched_barrier(0);
      __builtin_amdgcn_s_barrier();          // readers of B slot sc&1 done
      __builtin_amdgcn_sched_barrier(0);
      if (sc + 2 < NS) issueB(sc + 2);       // overwrites B slot sc&1 safely
    }
  }
  const int rb = bm * 128 + wm * 64 + ((lane >> 4) << 2);
  const int cb = bn * 256 + wn * 64 + frow;
#pragma unroll
  for (int n = 0; n < 4; n++) {
    const int col = cb + n * 16;
    const float bv = bias[col];
#pragma unroll
    for (int m = 0; m < 4; m++)
#pragma unroll
      for (int i = 0; i < 4; i++) {
        const int row = rb + m * 16 + i;
        C[(size_t)row * ldcE + ccol0 + col] = f2b(acc[m][n][i] + bv);
      }
  }
}

// ---- 128x128 m97-structure GEMM for cls layer (N=50) + fused score scatter ----
__global__ __launch_bounds__(256)
void gemm_cls(const unsigned short* __restrict__ A, int lda,
              const unsigned short* __restrict__ Bt,
              const float* __restrict__ bias,
              float* __restrict__ C,
              int Ktot,
              const int* __restrict__ pidx,
              unsigned long long* __restrict__ scat) {
  __shared__ unsigned short ldsA[128 * 64];
  __shared__ unsigned short ldsB[128 * 64];
  const int tid = threadIdx.x;
  const int lane = tid & 63, wid = tid >> 6;
  const int cpx = gridDim.x >> 3;
  const int bm = (blockIdx.x & 7) * cpx + (blockIdx.x >> 3);

  const int srow = wid * 32 + (lane >> 3);
  const int skof = (lane & 7) * 8;
  const unsigned short* ag = A + (size_t)(bm * 128 + srow) * lda + skof;
  const unsigned short* bg = Bt + (size_t)srow * Ktot + skof;

  f32x4 acc[4][4];
#pragma unroll
  for (int m = 0; m < 4; m++)
#pragma unroll
    for (int n = 0; n < 4; n++) acc[m][n] = (f32x4){0.f, 0.f, 0.f, 0.f};

  const int wm = wid >> 1, wn = wid & 1;
  const int frow = lane & 15;
  const int kgrp = (lane >> 4) << 3;

  for (int kt = 0; kt < Ktot; kt += 64) {
#pragma unroll
    for (int i = 0; i < 4; i++) {
      async_copy16(ag + (size_t)i * 8 * lda + kt, &ldsA[wid * 2048 + i * 512]);
      async_copy16(bg + (size_t)i * 8 * Ktot + kt, &ldsB[wid * 2048 + i * 512]);
    }
    __syncthreads();
#pragma unroll
    for (int kk = 0; kk < 64; kk += 32) {
      bf16x8 af[4], bfr[4];
#pragma unroll
      for (int m = 0; m < 4; m++)
        af[m] = *(const bf16x8*)&ldsA[(wm * 64 + m * 16 + frow) * 64 + kk + kgrp];
#pragma unroll
      for (int n = 0; n < 4; n++)
        bfr[n] = *(const bf16x8*)&ldsB[(wn * 64 + n * 16 + frow) * 64 + kk + kgrp];
#pragma unroll
      for (int m = 0; m < 4; m++)
#pragma unroll
        for (int n = 0; n < 4; n++)
          acc[m][n] = __builtin_amdgcn_mfma_f32_16x16x32_bf16(af[m], bfr[n], acc[m][n], 0, 0, 0);
    }
    __syncthreads();
  }
  const int rb = bm * 128 + wm * 64 + ((lane >> 4) << 2);
#pragma unroll
  for (int n = 0; n < 4; n++) {
    const int col = wn * 64 + frow + n * 16;
    const float bv = (col < OUTC) ? bias[col] : 0.f;
#pragma unroll
    for (int m = 0; m < 4; m++)
#pragma unroll
      for (int i = 0; i < 4; i++) {
        const int row = rb + m * 16 + i;
        if (col < OUTC) C[(size_t)row * OUTC + col] = acc[m][n][i] + bv;
      }
  }
  // fused score: wn==0 waves hold cols 0..63 of their 64 rows
  if (wn == 0) {
#pragma unroll
    for (int m = 0; m < 4; m++)
#pragma unroll
      for (int i = 0; i < 4; i++) {
        float mx = -1e30f;
#pragma unroll
        for (int n = 0; n < 4; n++) {
          const int col = n * 16 + frow;
          float v = acc[m][n][i] + ((col < OUTC) ? bias[col] : 0.f);
          if (col < OUTC) mx = fmaxf(mx, v);
        }
        mx = fmaxf(mx, __shfl_xor(mx, 1));
        mx = fmaxf(mx, __shfl_xor(mx, 2));
        mx = fmaxf(mx, __shfl_xor(mx, 4));
        mx = fmaxf(mx, __shfl_xor(mx, 8));
        if (frow == 0) {
          const int row = rb + m * 16 + i;
          float sc = 1.f / (1.f + expf(-mx));
          int b = row >> 12, p = row & 4095;
          int s = pidx[2 * row], o = pidx[2 * row + 1];
          unsigned long long key = (((unsigned long long)(p + 1)) << 32) |
                                   (unsigned long long)__float_as_uint(sc);
          atomicMax(&scat[((size_t)(b * N_ + s) << 7) + o], key);
        }
      }
  }
}

__global__ void relmat_kernel(const unsigned long long* __restrict__ scat, float* __restrict__ out) {
  int i = blockIdx.x * blockDim.x + threadIdx.x;
  if (i >= B_ * N_ * N_) return;
  unsigned long long v = scat[i];
  out[i] = v ? __uint_as_float((unsigned)(v & 0xffffffffu)) : 0.f;
}

extern "C" void kernel_launch(void* const* d_in, const int* in_sizes, int n_in,
                              void* d_out, int out_size, void* d_ws, size_t ws_size,
                              hipStream_t stream) {
  const float* visual_feat = (const float*)d_in[0];
  const float* box_info    = (const float*)d_in[1];
  const float* pred_logits = (const float*)d_in[2];
  const int*   pair_idx    = (const int*)d_in[3];
  const float* obj_sem_w   = (const float*)d_in[4];
  const float* pos_w1 = (const float*)d_in[5];
  const float* pos_b1 = (const float*)d_in[6];
  const float* pos_w2 = (const float*)d_in[7];
  const float* pos_b2 = (const float*)d_in[8];
  const float* vis_w  = (const float*)d_in[9];
  const float* vis_b  = (const float*)d_in[10];
  const float* geo_w  = (const float*)d_in[11];
  const float* geo_b  = (const float*)d_in[12];
  const float* fus_g  = (const float*)d_in[13];
  const float* fus_bt = (const float*)d_in[14];
  const float* fus_w  = (const float*)d_in[15];
  const float* fus_b  = (const float*)d_in[16];
  const float* cls_g  = (const float*)d_in[17];
  const float* cls_bt = (const float*)d_in[18];
  const float* cls_w  = (const float*)d_in[19];
  const float* cls_b  = (const float*)d_in[20];

  char* ws = (char*)d_ws;
  size_t off = 0;
  auto alloc = [&](size_t bytes) { char* p = ws + off; off += (bytes + 255) & ~(size_t)255; return p; };
  unsigned short* fused = (unsigned short*)alloc((size_t)M_ * 1024 * 2);      // 134 MB
  unsigned short* fused2 = (unsigned short*)alloc((size_t)M_ * 512 * 2);      // 67 MB
  unsigned short* nodeFb = (unsigned short*)alloc((size_t)B_ * N_ * NODEF * 2);
  unsigned short* wT_vis = (unsigned short*)alloc((size_t)512 * 1024 * 2);
  unsigned short* wT_geo = (unsigned short*)alloc((size_t)512 * KGEOP * 2);
  unsigned short* wT_fus = (unsigned short*)alloc((size_t)512 * 1024 * 2);
  unsigned short* wT_cls = (unsigned short*)alloc((size_t)128 * 512 * 2);
  unsigned long long* scat = (unsigned long long*)alloc((size_t)B_ * N_ * N_ * 8);

  float* out_logits = (float*)d_out;
  float* out_rel = out_logits + (size_t)M_ * OUTC;

  prep_kernel<<<dim3((PREP_TOT + 255) / 256), 256, 0, stream>>>(
      (uint4*)scat, vis_w, wT_vis, geo_w, wT_geo, fus_w, wT_fus, cls_w, wT_cls);
  node_kernel<<<dim3(B_ * N_), 128, 0, stream>>>(box_info, pred_logits, obj_sem_w,
                                                 pos_w1, pos_b1, pos_w2, pos_b2, nodeFb);
  // geo GEMM with fused pair-gather (A from nodeFb via per-lane gload_lds src)
  gemm256r<1><<<dim3(512), 512, 0, stream>>>(nullptr, 0, wT_geo, KGEOP, geo_b,
                                             fused, 1024, 512, KGEOP / 32, 2,
                                             pair_idx, nodeFb, (const unsigned short*)scat);
  // vis: 128x256 halved-acc ring-2 GEMM with fused f32->relu->bf16 (2 blocks/CU target)
  gemm256f3<<<dim3(1024), 512, 0, stream>>>(visual_feat, wT_vis, vis_b,
                                            fused, 1024, 0, 2);
  ln_relu_kernel<1024><<<dim3(M_ / 4), 256, 0, stream>>>(fused, fus_g, fus_bt);
  gemm256r<0><<<dim3(512), 512, 0, stream>>>(fused, 1024, wT_fus, 1024, fus_b,
                                             fused2, 512, 0, 1024 / 32, 2,
                                             nullptr, nullptr, nullptr);
  ln_relu_kernel<512><<<dim3(M_ / 4), 256, 0, stream>>>(fused2, cls_g, cls_bt);
  gemm_cls<<<dim3(512), 256, 0, stream>>>(fused2, 512, wT_cls, cls_b,
                                          out_logits, 512, pair_idx, scat);
  relmat_kernel<<<dim3((B_ * N_ * N_) / 256), 256, 0, stream>>>(scat, out_rel);
}

// Round 16
// 412.966 us; speedup vs baseline: 1.2255x; 1.0402x over previous
//
#include <hip/hip_runtime.h>
#include <cstdint>

#define B_    16
#define N_    128
#define P_    4096
#define M_    65536     // B_*P_
#define DIN   1024
#define DHID  512
#define DGEO  128
#define DEMB  200
#define NODEF 328       // DGEO + DEMB
#define NOBJ  151
#define OUTC  50
#define KGEO  656
#define KGEOP 672       // geo K padded to multiple of 32 (ring BK=32)

typedef __attribute__((ext_vector_type(8))) short bf16x8;
typedef __attribute__((ext_vector_type(4))) float f32x4;

typedef __attribute__((address_space(3))) unsigned char lds_u8;
typedef __attribute__((address_space(1))) unsigned char glb_u8;

static __device__ __forceinline__ void async_copy16(const void* g, void* l) {
  __builtin_amdgcn_global_load_lds((const glb_u8*)g, (lds_u8*)l, 16, 0, 0);
}

static __device__ __forceinline__ unsigned short f2b(float f) {
  union { float f; unsigned u; } v; v.f = f;
  unsigned r = v.u + 0x7fffu + ((v.u >> 16) & 1u);
  return (unsigned short)(r >> 16);
}
static __device__ __forceinline__ float b2f(unsigned short b) {
  union { unsigned u; float f; } v; v.u = ((unsigned)b) << 16;
  return v.f;
}
static __device__ __forceinline__ unsigned pack2(float a, float b) {
  return (unsigned)f2b(a) | ((unsigned)f2b(b) << 16);
}
static __device__ __forceinline__ void unpack8(uint4 raw, float* x) {
  x[0] = b2f(raw.x & 0xffffu); x[1] = b2f(raw.x >> 16);
  x[2] = b2f(raw.y & 0xffffu); x[3] = b2f(raw.y >> 16);
  x[4] = b2f(raw.z & 0xffffu); x[5] = b2f(raw.z >> 16);
  x[6] = b2f(raw.w & 0xffffu); x[7] = b2f(raw.w >> 16);
}

// ---- merged prologue: zero scat + all 4 weight transposes in one launch ----
#define ZN   131072                    // scat zero, uint4 count (2 MB)
#define TV   (512 * 1024)              // wT_vis elems
#define TG   (512 * KGEOP)             // wT_geo elems
#define TF   (512 * 1024)              // wT_fus elems
#define TC   (128 * 512)               // wT_cls elems
#define PREP_TOT (ZN + TV + TG + TF + TC)
__global__ __launch_bounds__(256)
void prep_kernel(uint4* __restrict__ scat,
                 const float* __restrict__ vis_w, unsigned short* __restrict__ wT_vis,
                 const float* __restrict__ geo_w, unsigned short* __restrict__ wT_geo,
                 const float* __restrict__ fus_w, unsigned short* __restrict__ wT_fus,
                 const float* __restrict__ cls_w, unsigned short* __restrict__ wT_cls) {
  int idx = blockIdx.x * 256 + threadIdx.x;
  if (idx < ZN) { scat[idx] = make_uint4(0, 0, 0, 0); return; }
  idx -= ZN;
  if (idx < TV) {
    int n = idx >> 10, k = idx & 1023;
    wT_vis[idx] = f2b(vis_w[(size_t)k * 512 + n]);
    return;
  }
  idx -= TV;
  if (idx < TG) {
    int n = idx / KGEOP, k = idx - n * KGEOP;
    wT_geo[idx] = (k < KGEO) ? f2b(geo_w[(size_t)k * 512 + n]) : 0;
    return;
  }
  idx -= TG;
  if (idx < TF) {
    int n = idx >> 10, k = idx & 1023;
    wT_fus[idx] = f2b(fus_w[(size_t)k * 512 + n]);
    return;
  }
  idx -= TF;
  if (idx < TC) {
    int n = idx >> 9, k = idx & 511;
    wT_cls[idx] = (n < OUTC) ? f2b(cls_w[(size_t)k * OUTC + n]) : 0;
  }
}

// ---- per-node features (relu'd, bf16): nodeFb[node] = [relu(pos)(128), relu(sem)(200)] ----
__global__ __launch_bounds__(128)
void node_kernel(const float* __restrict__ box, const float* __restrict__ plog,
                 const float* __restrict__ semw,
                 const float* __restrict__ w1, const float* __restrict__ b1,
                 const float* __restrict__ w2, const float* __restrict__ b2,
                 unsigned short* __restrict__ nodeFb) {
  const int node = blockIdx.x;
  const int t = threadIdx.x;
  __shared__ float sBox[9];
  __shared__ float sH[128];
  __shared__ float sE[NOBJ];
  __shared__ float sRed[4];
  if (t < 9) sBox[t] = box[node * 9 + t];
  float l0 = (t < NOBJ) ? plog[node * NOBJ + t] : -1e30f;
  float l1 = (t + 128 < NOBJ) ? plog[node * NOBJ + t + 128] : -1e30f;
  __syncthreads();
  float h = b1[t];
#pragma unroll
  for (int i = 0; i < 9; i++) h = fmaf(sBox[i], w1[i * 128 + t], h);
  h = fmaxf(h, 0.f);
  sH[t] = h;
  float mx = fmaxf(l0, l1);
#pragma unroll
  for (int off = 32; off >= 1; off >>= 1) mx = fmaxf(mx, __shfl_xor(mx, off));
  if ((t & 63) == 0) sRed[t >> 6] = mx;
  __syncthreads();
  mx = fmaxf(sRed[0], sRed[1]);
  float e0 = (t < NOBJ) ? expf(l0 - mx) : 0.f;
  float e1 = (t + 128 < NOBJ) ? expf(l1 - mx) : 0.f;
  if (t < NOBJ) sE[t] = e0;
  if (t + 128 < NOBJ) sE[t + 128] = e1;
  float sm = e0 + e1;
#pragma unroll
  for (int off = 32; off >= 1; off >>= 1) sm += __shfl_xor(sm, off);
  if ((t & 63) == 0) sRed[2 + (t >> 6)] = sm;
  __syncthreads();
  const float inv = 1.f / (sRed[2] + sRed[3]);
  float pv = b2[t];
  for (int i = 0; i < 128; i++) pv = fmaf(sH[i], w2[i * 128 + t], pv);
  nodeFb[(size_t)node * NODEF + t] = f2b(fmaxf(pv, 0.f));
  float a0 = 0.f, a1 = 0.f;
  const int d1 = (t + 128 < DEMB) ? (t + 128) : 0;
  for (int i = 0; i < NOBJ; i++) {
    float e = sE[i];
    a0 = fmaf(e, semw[i * DEMB + t], a0);
    a1 = fmaf(e, semw[i * DEMB + d1], a1);
  }
  nodeFb[(size_t)node * NODEF + 128 + t] = f2b(fmaxf(a0 * inv, 0.f));
  if (t + 128 < DEMB) nodeFb[(size_t)node * NODEF + 128 + t + 128] = f2b(fmaxf(a1 * inv, 0.f));
}

// ---- fused LayerNorm + ReLU, in place, wave per row ----
template<int D>
__global__ __launch_bounds__(256)
void ln_relu_kernel(unsigned short* __restrict__ X,
                    const float* __restrict__ g, const float* __restrict__ bta) {
  constexpr int C = D / 64;
  const int lane = threadIdx.x & 63, wv = threadIdx.x >> 6;
  const size_t row = (size_t)blockIdx.x * 4 + wv;
  unsigned short* xp = X + row * D + lane * C;
  float x[C];
#pragma unroll
  for (int c = 0; c < C; c += 8) {
    uint4 raw = *(const uint4*)(xp + c);
    unpack8(raw, x + c);
  }
  float s = 0.f, s2 = 0.f;
#pragma unroll
  for (int q = 0; q < C; q++) { s += x[q]; s2 = fmaf(x[q], x[q], s2); }
#pragma unroll
  for (int off = 32; off >= 1; off >>= 1) { s += __shfl_xor(s, off); s2 += __shfl_xor(s2, off); }
  const float mu = s / D;
  const float rs = rsqrtf(s2 / D - mu * mu + 1e-5f);
  const float* gp = g + lane * C;
  const float* bp = bta + lane * C;
#pragma unroll
  for (int c = 0; c < C; c += 8) {
    float4 g0 = *(const float4*)(gp + c), g1 = *(const float4*)(gp + c + 4);
    float4 t0 = *(const float4*)(bp + c), t1 = *(const float4*)(bp + c + 4);
    float y0 = fmaxf(fmaf((x[c + 0] - mu) * rs, g0.x, t0.x), 0.f);
    float y1 = fmaxf(fmaf((x[c + 1] - mu) * rs, g0.y, t0.y), 0.f);
    float y2 = fmaxf(fmaf((x[c + 2] - mu) * rs, g0.z, t0.z), 0.f);
    float y3 = fmaxf(fmaf((x[c + 3] - mu) * rs, g0.w, t0.w), 0.f);
    float y4 = fmaxf(fmaf((x[c + 4] - mu) * rs, g1.x, t1.x), 0.f);
    float y5 = fmaxf(fmaf((x[c + 5] - mu) * rs, g1.y, t1.y), 0.f);
    float y6 = fmaxf(fmaf((x[c + 6] - mu) * rs, g1.z, t1.z), 0.f);
    float y7 = fmaxf(fmaf((x[c + 7] - mu) * rs, g1.w, t1.w), 0.f);
    uint4 u;
    u.x = pack2(y0, y1); u.y = pack2(y2, y3);
    u.z = pack2(y4, y5); u.w = pack2(y6, y7);
    *(uint4*)(xp + c) = u;
  }
}

// ---- pair-XCD swizzle: bn-siblings (bid=2k,2k+1) land on the SAME XCD ----
// bijective for nwg % 16 == 0
static __device__ __forceinline__ int pair_swz(int bid, int nwg) {
  const int cpx2 = nwg >> 4;                 // pairs per XCD
  const int pr = bid >> 1, q = bid & 1;
  return (((pr & 7) * cpx2) + (pr >> 3)) * 2 + q;
}

// ---- 128x256 ring-2 GEMM, all-gload_lds staging, halved acc (2 blocks/CU) ----
// 512 thr (8 waves, 2M x 4N), wave tile 64x64 -> acc[4][4] = 64 AGPR.
// LDS = A 2x8K + B 2x16K = 48 KB. Per stage: 1 A + 2 B gload_lds = 3 vm events.
// Ring-2 ledger (R9/R15-proven; stage(s+2) issued AFTER barrier-2 of phase s):
//   head of phase s: outstanding = {s, s+1} = 6 -> vmcnt(3) drains stage s;
//   s==NS-1: only stage s outstanding -> vmcnt(0) (R3 bug class).
// Swizzle (gemm256r's measured-0-conflict pair): src kslot (t&3)^((t>>3)&3),
// read koff ((lane>>4)^((frow>>1)&3))<<4.
// MODE 0: A plain bf16 [M][ldaE]. MODE 2: A per-lane gathered pair rows
// (subj 0..327 | obj 328..655 | zero; 16B chunks never straddle: 328,656 are x8).
template<int MODE>
__global__ __launch_bounds__(512, 4)
void gemm128x256g(const unsigned short* __restrict__ A, int ldaE,
                  const unsigned short* __restrict__ Bt, int Ktot,
                  const float* __restrict__ bias,
                  unsigned short* __restrict__ C, int ldcE, int ccol0,
                  int NS, int NBN,
                  const int* __restrict__ pidx,
                  const unsigned short* __restrict__ nodeFb,
                  const unsigned short* __restrict__ zsrc) {
  __shared__ __align__(16) unsigned char smem[49152];   // A 2x8K | B 2x16K @16K
  const int tid = threadIdx.x;
  const int lane = tid & 63, w = tid >> 6;
  const int swz = pair_swz(blockIdx.x, gridDim.x);
  const int bm = swz / NBN, bn = swz - bm * NBN;

  const int sslot = (tid & 3) ^ ((tid >> 3) & 3);       // pre-swizzled source k-slot
  const int srow = tid >> 2;                            // 0..127
  const size_t ldaBy = (size_t)ldaE * 2, ldbBy = (size_t)Ktot * 2;
  const unsigned char* aG = (const unsigned char*)A + (size_t)(bm * 128 + srow) * ldaBy + sslot * 16;
  const unsigned char* bG = (const unsigned char*)Bt + (size_t)(bn * 256 + srow) * ldbBy + sslot * 16;

  const unsigned short* nbS = nullptr;
  const unsigned short* nbO = nullptr;
  if (MODE == 2) {
    int pr = bm * 128 + srow;
    int2 so = *(const int2*)(pidx + 2 * pr);
    int b = pr >> 12;
    nbS = nodeFb + (size_t)((b << 7) + so.x) * NODEF;
    nbO = nodeFb + (size_t)((b << 7) + so.y) * NODEF;
  }

  auto stage = [&](int s) {
    const int slot = s & 1;
    unsigned char* la = smem + slot * 8192 + w * 1024;
    unsigned char* lb = smem + 16384 + slot * 16384 + w * 1024;
    if (MODE == 0) {
      async_copy16(aG + (size_t)s * 64, la);
    } else {
      const int e = s * 32 + sslot * 8;
      uintptr_t sel = (e < NODEF) ? (uintptr_t)(nbS + e)
                    : (e < KGEO)  ? (uintptr_t)(nbO + (e - NODEF))
                                  : (uintptr_t)zsrc;
      async_copy16((const void*)sel, la);
    }
    const unsigned char* sb = bG + (size_t)s * 64;
    async_copy16(sb, lb);
    async_copy16(sb + 128 * ldbBy, lb + 8192);
  };

  const int wm = w >> 2, wn = w & 3;                    // 2M x 4N waves, 64x64 each
  const int frow = lane & 15;
  const int colb = (((lane >> 4) ^ ((frow >> 1) & 3)) << 4);
  const int aRowB = (wm * 64 + frow) * 64;
  const int bRowB = (wn * 64 + frow) * 64;

  f32x4 acc[4][4];
#pragma unroll
  for (int m = 0; m < 4; m++)
#pragma unroll
    for (int n = 0; n < 4; n++) acc[m][n] = (f32x4){0.f, 0.f, 0.f, 0.f};

  stage(0); stage(1);
#pragma unroll 1
  for (int s = 0; s < NS; ++s) {
    if (s == NS - 1) asm volatile("s_waitcnt vmcnt(0)" ::: "memory");
    else             asm volatile("s_waitcnt vmcnt(3)" ::: "memory");
    __builtin_amdgcn_s_barrier();
    __builtin_amdgcn_sched_barrier(0);
    const unsigned char* ab = smem + (s & 1) * 8192;
    const unsigned char* bb = smem + 16384 + (s & 1) * 16384;
    bf16x8 af[4];
#pragma unroll
    for (int m = 0; m < 4; m++) af[m] = *(const bf16x8*)(ab + aRowB + m * 1024 + colb);
    __builtin_amdgcn_s_setprio(1);
#pragma unroll
    for (int n = 0; n < 4; n++) {
      bf16x8 bf = *(const bf16x8*)(bb + bRowB + n * 1024 + colb);
#pragma unroll
      for (int m = 0; m < 4; m++)
        acc[m][n] = __builtin_amdgcn_mfma_f32_16x16x32_bf16(af[m], bf, acc[m][n], 0, 0, 0);
    }
    __builtin_amdgcn_s_setprio(0);
    __builtin_amdgcn_sched_barrier(0);
    __builtin_amdgcn_s_barrier();               // readers of slot s&1 done
    __builtin_amdgcn_sched_barrier(0);
    if (s + 2 < NS) stage(s + 2);               // overwrites slot s&1 safely
  }
  const int rb = bm * 128 + wm * 64 + ((lane >> 4) << 2);
  const int cb = bn * 256 + wn * 64 + frow;
#pragma unroll
  for (int n = 0; n < 4; n++) {
    const int col = cb + n * 16;
    const float bv = bias[col];
#pragma unroll
    for (int m = 0; m < 4; m++)
#pragma unroll
      for (int i = 0; i < 4; i++) {
        const int row = rb + m * 16 + i;
        C[(size_t)row * ldcE + ccol0 + col] = f2b(acc[m][n][i] + bv);
      }
  }
}

// ---- 128x256 ring-2 GEMM, A f32+relu+cvt reg-staged, halved acc (R15-proven) ----
__global__ __launch_bounds__(512, 4)
void gemm256f3(const float* __restrict__ A,            // f32, lda = 1024
               const unsigned short* __restrict__ Bt,  // [512][1024] bf16
               const float* __restrict__ bias,
               unsigned short* __restrict__ C, int ldcE, int ccol0,
               int NBN) {
  constexpr int NS = 32;                               // K=1024 / BK=32
  __shared__ __align__(16) unsigned char smem[49152];  // A 2x8K | B 2x16K @16K
  const int tid = threadIdx.x;
  const int lane = tid & 63, w = tid >> 6;
  const int swz = pair_swz(blockIdx.x, gridDim.x);
  const int bm = swz / NBN, bn = swz - bm * NBN;       // bm 0..511, bn 0..1

  const int sslot = (tid & 3) ^ ((tid >> 3) & 3);      // source k-slot (pre-swizzle)
  const int srow = tid >> 2;                           // 0..127
  const float* aG = A + (size_t)(bm * 128 + srow) * 1024 + sslot * 8;
  const unsigned char* bG = (const unsigned char*)Bt + (size_t)(bn * 256 + srow) * 2048 + sslot * 16;
  unsigned char* laBase = smem + srow * 64 + (tid & 3) * 16;
  unsigned char* lbBase = smem + 16384 + w * 1024;

  uint4 ra0[2], ra1[2];                                // 2 static reg sets

  auto issueA = [&](int s, uint4* ra) {
    const float* p0 = aG + (size_t)s * 32;
    ra[0] = *(const uint4*)(p0);
    ra[1] = *(const uint4*)(p0 + 4);
  };
  auto issueB = [&](int s) {
    const int slot = s & 1;
    const unsigned char* sb = bG + (size_t)s * 64;
    async_copy16(sb, lbBase + slot * 16384);
    async_copy16(sb + 128 * 2048, lbBase + slot * 16384 + 8192);
  };
  auto writeA = [&](int s, const uint4* ra) {
    const int slot = s & 1;
    float x0 = fmaxf(__uint_as_float(ra[0].x), 0.f);
    float x1 = fmaxf(__uint_as_float(ra[0].y), 0.f);
    float x2 = fmaxf(__uint_as_float(ra[0].z), 0.f);
    float x3 = fmaxf(__uint_as_float(ra[0].w), 0.f);
    float x4 = fmaxf(__uint_as_float(ra[1].x), 0.f);
    float x5 = fmaxf(__uint_as_float(ra[1].y), 0.f);
    float x6 = fmaxf(__uint_as_float(ra[1].z), 0.f);
    float x7 = fmaxf(__uint_as_float(ra[1].w), 0.f);
    uint4 u;
    u.x = pack2(x0, x1); u.y = pack2(x2, x3);
    u.z = pack2(x4, x5); u.w = pack2(x6, x7);
    *(uint4*)(laBase + slot * 8192) = u;
  };

  const int wm = w >> 2, wn = w & 3;                   // 2M x 4N waves, 64x64 each
  const int frow = lane & 15;
  const int colb = (((lane >> 4) ^ ((frow >> 1) & 3)) << 4);
  const int aRowB = (wm * 64 + frow) * 64;
  const int bRowB = (wn * 64 + frow) * 64;

  f32x4 acc[4][4];
#pragma unroll
  for (int m = 0; m < 4; m++)
#pragma unroll
    for (int n = 0; n < 4; n++) acc[m][n] = (f32x4){0.f, 0.f, 0.f, 0.f};

  issueA(0, ra0); issueB(0);
  issueA(1, ra1); issueB(1);

#pragma unroll 1
  for (int s = 0; s < NS; s += 2) {
#pragma unroll
    for (int half = 0; half < 2; half++) {
      const int sc = s + half;
      uint4* raC = half ? ra1 : ra0;
      if (sc == NS - 1) asm volatile("s_waitcnt vmcnt(0)" ::: "memory");
      else              asm volatile("s_waitcnt vmcnt(4)" ::: "memory");
      __builtin_amdgcn_sched_barrier(0);
      writeA(sc, raC);                       // slot sc&1: readers done at sc-2
      if (sc + 2 < NS) issueA(sc + 2, raC);  // regs only — safe before barrier
      asm volatile("s_waitcnt lgkmcnt(0)" ::: "memory");
      __builtin_amdgcn_s_barrier();
      __builtin_amdgcn_sched_barrier(0);
      const unsigned char* ab = smem + (sc & 1) * 8192;
      const unsigned char* bb = smem + 16384 + (sc & 1) * 16384;
      bf16x8 af[4];
#pragma unroll
      for (int m = 0; m < 4; m++) af[m] = *(const bf16x8*)(ab + aRowB + m * 1024 + colb);
      __builtin_amdgcn_s_setprio(1);
#pragma unroll
      for (int n = 0; n < 4; n++) {
        bf16x8 bf = *(const bf16x8*)(bb + bRowB + n * 1024 + colb);
#pragma unroll
        for (int m = 0; m < 4; m++)
          acc[m][n] = __builtin_amdgcn_mfma_f32_16x16x32_bf16(af[m], bf, acc[m][n], 0, 0, 0);
      }
      __builtin_amdgcn_s_setprio(0);
      __builtin_amdgcn_sched_barrier(0);
      __builtin_amdgcn_s_barrier();          // readers of B slot sc&1 done
      __builtin_amdgcn_sched_barrier(0);
      if (sc + 2 < NS) issueB(sc + 2);       // overwrites B slot sc&1 safely
    }
  }
  const int rb = bm * 128 + wm * 64 + ((lane >> 4) << 2);
  const int cb = bn * 256 + wn * 64 + frow;
#pragma unroll
  for (int n = 0; n < 4; n++) {
    const int col = cb + n * 16;
    const float bv = bias[col];
#pragma unroll
    for (int m = 0; m < 4; m++)
#pragma unroll
      for (int i = 0; i < 4; i++) {
        const int row = rb + m * 16 + i;
        C[(size_t)row * ldcE + ccol0 + col] = f2b(acc[m][n][i] + bv);
      }
  }
}

// ---- 128x128 m97-structure GEMM for cls layer (N=50) + fused score scatter ----
__global__ __launch_bounds__(256)
void gemm_cls(const unsigned short* __restrict__ A, int lda,
              const unsigned short* __restrict__ Bt,
              const float* __restrict__ bias,
              float* __restrict__ C,
              int Ktot,
              const int* __restrict__ pidx,
              unsigned long long* __restrict__ scat) {
  __shared__ unsigned short ldsA[128 * 64];
  __shared__ unsigned short ldsB[128 * 64];
  const int tid = threadIdx.x;
  const int lane = tid & 63, wid = tid >> 6;
  const int cpx = gridDim.x >> 3;
  const int bm = (blockIdx.x & 7) * cpx + (blockIdx.x >> 3);

  const int srow = wid * 32 + (lane >> 3);
  const int skof = (lane & 7) * 8;
  const unsigned short* ag = A + (size_t)(bm * 128 + srow) * lda + skof;
  const unsigned short* bg = Bt + (size_t)srow * Ktot + skof;

  f32x4 acc[4][4];
#pragma unroll
  for (int m = 0; m < 4; m++)
#pragma unroll
    for (int n = 0; n < 4; n++) acc[m][n] = (f32x4){0.f, 0.f, 0.f, 0.f};

  const int wm = wid >> 1, wn = wid & 1;
  const int frow = lane & 15;
  const int kgrp = (lane >> 4) << 3;

  for (int kt = 0; kt < Ktot; kt += 64) {
#pragma unroll
    for (int i = 0; i < 4; i++) {
      async_copy16(ag + (size_t)i * 8 * lda + kt, &ldsA[wid * 2048 + i * 512]);
      async_copy16(bg + (size_t)i * 8 * Ktot + kt, &ldsB[wid * 2048 + i * 512]);
    }
    __syncthreads();
#pragma unroll
    for (int kk = 0; kk < 64; kk += 32) {
      bf16x8 af[4], bfr[4];
#pragma unroll
      for (int m = 0; m < 4; m++)
        af[m] = *(const bf16x8*)&ldsA[(wm * 64 + m * 16 + frow) * 64 + kk + kgrp];
#pragma unroll
      for (int n = 0; n < 4; n++)
        bfr[n] = *(const bf16x8*)&ldsB[(wn * 64 + n * 16 + frow) * 64 + kk + kgrp];
#pragma unroll
      for (int m = 0; m < 4; m++)
#pragma unroll
        for (int n = 0; n < 4; n++)
          acc[m][n] = __builtin_amdgcn_mfma_f32_16x16x32_bf16(af[m], bfr[n], acc[m][n], 0, 0, 0);
    }
    __syncthreads();
  }
  const int rb = bm * 128 + wm * 64 + ((lane >> 4) << 2);
#pragma unroll
  for (int n = 0; n < 4; n++) {
    const int col = wn * 64 + frow + n * 16;
    const float bv = (col < OUTC) ? bias[col] : 0.f;
#pragma unroll
    for (int m = 0; m < 4; m++)
#pragma unroll
      for (int i = 0; i < 4; i++) {
        const int row = rb + m * 16 + i;
        if (col < OUTC) C[(size_t)row * OUTC + col] = acc[m][n][i] + bv;
      }
  }
  // fused score: wn==0 waves hold cols 0..63 of their 64 rows
  if (wn == 0) {
#pragma unroll
    for (int m = 0; m < 4; m++)
#pragma unroll
      for (int i = 0; i < 4; i++) {
        float mx = -1e30f;
#pragma unroll
        for (int n = 0; n < 4; n++) {
          const int col = n * 16 + frow;
          float v = acc[m][n][i] + ((col < OUTC) ? bias[col] : 0.f);
          if (col < OUTC) mx = fmaxf(mx, v);
        }
        mx = fmaxf(mx, __shfl_xor(mx, 1));
        mx = fmaxf(mx, __shfl_xor(mx, 2));
        mx = fmaxf(mx, __shfl_xor(mx, 4));
        mx = fmaxf(mx, __shfl_xor(mx, 8));
        if (frow == 0) {
          const int row = rb + m * 16 + i;
          float sc = 1.f / (1.f + expf(-mx));
          int b = row >> 12, p = row & 4095;
          int s = pidx[2 * row], o = pidx[2 * row + 1];
          unsigned long long key = (((unsigned long long)(p + 1)) << 32) |
                                   (unsigned long long)__float_as_uint(sc);
          atomicMax(&scat[((size_t)(b * N_ + s) << 7) + o], key);
        }
      }
  }
}

__global__ void relmat_kernel(const unsigned long long* __restrict__ scat, float* __restrict__ out) {
  int i = blockIdx.x * blockDim.x + threadIdx.x;
  if (i >= B_ * N_ * N_) return;
  unsigned long long v = scat[i];
  out[i] = v ? __uint_as_float((unsigned)(v & 0xffffffffu)) : 0.f;
}

extern "C" void kernel_launch(void* const* d_in, const int* in_sizes, int n_in,
                              void* d_out, int out_size, void* d_ws, size_t ws_size,
                              hipStream_t stream) {
  const float* visual_feat = (const float*)d_in[0];
  const float* box_info    = (const float*)d_in[1];
  const float* pred_logits = (const float*)d_in[2];
  const int*   pair_idx    = (const int*)d_in[3];
  const float* obj_sem_w   = (const float*)d_in[4];
  const float* pos_w1 = (const float*)d_in[5];
  const float* pos_b1 = (const float*)d_in[6];
  const float* pos_w2 = (const float*)d_in[7];
  const float* pos_b2 = (const float*)d_in[8];
  const float* vis_w  = (const float*)d_in[9];
  const float* vis_b  = (const float*)d_in[10];
  const float* geo_w  = (const float*)d_in[11];
  const float* geo_b  = (const float*)d_in[12];
  const float* fus_g  = (const float*)d_in[13];
  const float* fus_bt = (const float*)d_in[14];
  const float* fus_w  = (const float*)d_in[15];
  const float* fus_b  = (const float*)d_in[16];
  const float* cls_g  = (const float*)d_in[17];
  const float* cls_bt = (const float*)d_in[18];
  const float* cls_w  = (const float*)d_in[19];
  const float* cls_b  = (const float*)d_in[20];

  char* ws = (char*)d_ws;
  size_t off = 0;
  auto alloc = [&](size_t bytes) { char* p = ws + off; off += (bytes + 255) & ~(size_t)255; return p; };
  unsigned short* fused = (unsigned short*)alloc((size_t)M_ * 1024 * 2);      // 134 MB
  unsigned short* fused2 = (unsigned short*)alloc((size_t)M_ * 512 * 2);      // 67 MB
  unsigned short* nodeFb = (unsigned short*)alloc((size_t)B_ * N_ * NODEF * 2);
  unsigned short* wT_vis = (unsigned short*)alloc((size_t)512 * 1024 * 2);
  unsigned short* wT_geo = (unsigned short*)alloc((size_t)512 * KGEOP * 2);
  unsigned short* wT_fus = (unsigned short*)alloc((size_t)512 * 1024 * 2);
  unsigned short* wT_cls = (unsigned short*)alloc((size_t)128 * 512 * 2);
  unsigned long long* scat = (unsigned long long*)alloc((size_t)B_ * N_ * N_ * 8);

  float* out_logits = (float*)d_out;
  float* out_rel = out_logits + (size_t)M_ * OUTC;

  prep_kernel<<<dim3((PREP_TOT + 255) / 256), 256, 0, stream>>>(
      (uint4*)scat, vis_w, wT_vis, geo_w, wT_geo, fus_w, wT_fus, cls_w, wT_cls);
  node_kernel<<<dim3(B_ * N_), 128, 0, stream>>>(box_info, pred_logits, obj_sem_w,
                                                 pos_w1, pos_b1, pos_w2, pos_b2, nodeFb);
  // geo: 128x256 halved-acc gather GEMM -> fused[:,512:]
  gemm128x256g<2><<<dim3(1024), 512, 0, stream>>>(nullptr, 0, wT_geo, KGEOP, geo_b,
                                                  fused, 1024, 512, KGEOP / 32, 2,
                                                  pair_idx, nodeFb, (const unsigned short*)scat);
  // vis: 128x256 halved-acc ring-2 GEMM with fused f32->relu->bf16 (R15-proven)
  gemm256f3<<<dim3(1024), 512, 0, stream>>>(visual_feat, wT_vis, vis_b,
                                            fused, 1024, 0, 2);
  ln_relu_kernel<1024><<<dim3(M_ / 4), 256, 0, stream>>>(fused, fus_g, fus_bt);
  // fus: 128x256 halved-acc plain GEMM -> fused2
  gemm128x256g<0><<<dim3(1024), 512, 0, stream>>>(fused, 1024, wT_fus, 1024, fus_b,
                                                  fused2, 512, 0, 1024 / 32, 2,
                                                  nullptr, nullptr, nullptr);
  ln_relu_kernel<512><<<dim3(M_ / 4), 256, 0, stream>>>(fused2, cls_g, cls_bt);
  gemm_cls<<<dim3(512), 256, 0, stream>>>(fused2, 512, wT_cls, cls_b,
                                          out_logits, 512, pair_idx, scat);
  relmat_kernel<<<dim3((B_ * N_ * N_) / 256), 256, 0, stream>>>(scat, out_rel);
}

// Round 17
// 386.108 us; speedup vs baseline: 1.3108x; 1.0696x over previous
//
#include <hip/hip_runtime.h>
#include <cstdint>

#define B_    16
#define N_    128
#define P_    4096
#define M_    65536     // B_*P_
#define DIN   1024
#define DHID  512
#define DGEO  128
#define DEMB  200
#define NODEF 328       // DGEO + DEMB
#define NOBJ  151
#define OUTC  50
#define KGEO  656
#define KGEOP 672       // geo K padded to multiple of 32 (ring BK=32)

typedef __attribute__((ext_vector_type(8))) short bf16x8;
typedef __attribute__((ext_vector_type(4))) float f32x4;

typedef __attribute__((address_space(3))) unsigned char lds_u8;
typedef __attribute__((address_space(1))) unsigned char glb_u8;

static __device__ __forceinline__ void async_copy16(const void* g, void* l) {
  __builtin_amdgcn_global_load_lds((const glb_u8*)g, (lds_u8*)l, 16, 0, 0);
}

static __device__ __forceinline__ unsigned short f2b(float f) {
  union { float f; unsigned u; } v; v.f = f;
  unsigned r = v.u + 0x7fffu + ((v.u >> 16) & 1u);
  return (unsigned short)(r >> 16);
}
static __device__ __forceinline__ float b2f(unsigned short b) {
  union { unsigned u; float f; } v; v.u = ((unsigned)b) << 16;
  return v.f;
}
static __device__ __forceinline__ unsigned pack2(float a, float b) {
  return (unsigned)f2b(a) | ((unsigned)f2b(b) << 16);
}
static __device__ __forceinline__ void unpack8(uint4 raw, float* x) {
  x[0] = b2f(raw.x & 0xffffu); x[1] = b2f(raw.x >> 16);
  x[2] = b2f(raw.y & 0xffffu); x[3] = b2f(raw.y >> 16);
  x[4] = b2f(raw.z & 0xffffu); x[5] = b2f(raw.z >> 16);
  x[6] = b2f(raw.w & 0xffffu); x[7] = b2f(raw.w >> 16);
}

// ---- merged prologue: zero scat + all 4 weight transposes in one launch ----
#define ZN   131072                    // scat zero, uint4 count (2 MB)
#define TV   (512 * 1024)              // wT_vis elems
#define TG   (512 * KGEOP)             // wT_geo elems
#define TF   (512 * 1024)              // wT_fus elems
#define TC   (128 * 512)               // wT_cls elems
#define PREP_TOT (ZN + TV + TG + TF + TC)
__global__ __launch_bounds__(256)
void prep_kernel(uint4* __restrict__ scat,
                 const float* __restrict__ vis_w, unsigned short* __restrict__ wT_vis,
                 const float* __restrict__ geo_w, unsigned short* __restrict__ wT_geo,
                 const float* __restrict__ fus_w, unsigned short* __restrict__ wT_fus,
                 const float* __restrict__ cls_w, unsigned short* __restrict__ wT_cls) {
  int idx = blockIdx.x * 256 + threadIdx.x;
  if (idx < ZN) { scat[idx] = make_uint4(0, 0, 0, 0); return; }
  idx -= ZN;
  if (idx < TV) {
    int n = idx >> 10, k = idx & 1023;
    wT_vis[idx] = f2b(vis_w[(size_t)k * 512 + n]);
    return;
  }
  idx -= TV;
  if (idx < TG) {
    int n = idx / KGEOP, k = idx - n * KGEOP;
    wT_geo[idx] = (k < KGEO) ? f2b(geo_w[(size_t)k * 512 + n]) : 0;
    return;
  }
  idx -= TG;
  if (idx < TF) {
    int n = idx >> 10, k = idx & 1023;
    wT_fus[idx] = f2b(fus_w[(size_t)k * 512 + n]);
    return;
  }
  idx -= TF;
  if (idx < TC) {
    int n = idx >> 9, k = idx & 511;
    wT_cls[idx] = (n < OUTC) ? f2b(cls_w[(size_t)k * OUTC + n]) : 0;
  }
}

// ---- per-node features (relu'd, bf16): nodeFb[node] = [relu(pos)(128), relu(sem)(200)] ----
__global__ __launch_bounds__(128)
void node_kernel(const float* __restrict__ box, const float* __restrict__ plog,
                 const float* __restrict__ semw,
                 const float* __restrict__ w1, const float* __restrict__ b1,
                 const float* __restrict__ w2, const float* __restrict__ b2,
                 unsigned short* __restrict__ nodeFb) {
  const int node = blockIdx.x;
  const int t = threadIdx.x;
  __shared__ float sBox[9];
  __shared__ float sH[128];
  __shared__ float sE[NOBJ];
  __shared__ float sRed[4];
  if (t < 9) sBox[t] = box[node * 9 + t];
  float l0 = (t < NOBJ) ? plog[node * NOBJ + t] : -1e30f;
  float l1 = (t + 128 < NOBJ) ? plog[node * NOBJ + t + 128] : -1e30f;
  __syncthreads();
  float h = b1[t];
#pragma unroll
  for (int i = 0; i < 9; i++) h = fmaf(sBox[i], w1[i * 128 + t], h);
  h = fmaxf(h, 0.f);
  sH[t] = h;
  float mx = fmaxf(l0, l1);
#pragma unroll
  for (int off = 32; off >= 1; off >>= 1) mx = fmaxf(mx, __shfl_xor(mx, off));
  if ((t & 63) == 0) sRed[t >> 6] = mx;
  __syncthreads();
  mx = fmaxf(sRed[0], sRed[1]);
  float e0 = (t < NOBJ) ? expf(l0 - mx) : 0.f;
  float e1 = (t + 128 < NOBJ) ? expf(l1 - mx) : 0.f;
  if (t < NOBJ) sE[t] = e0;
  if (t + 128 < NOBJ) sE[t + 128] = e1;
  float sm = e0 + e1;
#pragma unroll
  for (int off = 32; off >= 1; off >>= 1) sm += __shfl_xor(sm, off);
  if ((t & 63) == 0) sRed[2 + (t >> 6)] = sm;
  __syncthreads();
  const float inv = 1.f / (sRed[2] + sRed[3]);
  float pv = b2[t];
  for (int i = 0; i < 128; i++) pv = fmaf(sH[i], w2[i * 128 + t], pv);
  nodeFb[(size_t)node * NODEF + t] = f2b(fmaxf(pv, 0.f));
  float a0 = 0.f, a1 = 0.f;
  const int d1 = (t + 128 < DEMB) ? (t + 128) : 0;
  for (int i = 0; i < NOBJ; i++) {
    float e = sE[i];
    a0 = fmaf(e, semw[i * DEMB + t], a0);
    a1 = fmaf(e, semw[i * DEMB + d1], a1);
  }
  nodeFb[(size_t)node * NODEF + 128 + t] = f2b(fmaxf(a0 * inv, 0.f));
  if (t + 128 < DEMB) nodeFb[(size_t)node * NODEF + 128 + t + 128] = f2b(fmaxf(a1 * inv, 0.f));
}

// ---- row stats for LN: mu, rsqrt(var+eps), wave per row over [M][1024] bf16 ----
__global__ __launch_bounds__(256)
void stats_kernel(const unsigned short* __restrict__ X, float* __restrict__ st) {
  const int lane = threadIdx.x & 63, wv = threadIdx.x >> 6;
  const size_t row = (size_t)blockIdx.x * 4 + wv;
  const unsigned short* xp = X + row * 1024 + lane * 16;
  float x[16];
  uint4 r0 = *(const uint4*)(xp);
  uint4 r1 = *(const uint4*)(xp + 8);
  unpack8(r0, x); unpack8(r1, x + 8);
  float s = 0.f, s2 = 0.f;
#pragma unroll
  for (int q = 0; q < 16; q++) { s += x[q]; s2 = fmaf(x[q], x[q], s2); }
#pragma unroll
  for (int off = 32; off >= 1; off >>= 1) { s += __shfl_xor(s, off); s2 += __shfl_xor(s2, off); }
  if (lane == 0) {
    float mu = s * (1.f / 1024.f);
    float var = s2 * (1.f / 1024.f) - mu * mu;
    ((float2*)st)[row] = make_float2(mu, rsqrtf(var + 1e-5f));
  }
}

// ---- fused LayerNorm + ReLU, in place, wave per row (kept for D=512) ----
template<int D>
__global__ __launch_bounds__(256)
void ln_relu_kernel(unsigned short* __restrict__ X,
                    const float* __restrict__ g, const float* __restrict__ bta) {
  constexpr int C = D / 64;
  const int lane = threadIdx.x & 63, wv = threadIdx.x >> 6;
  const size_t row = (size_t)blockIdx.x * 4 + wv;
  unsigned short* xp = X + row * D + lane * C;
  float x[C];
#pragma unroll
  for (int c = 0; c < C; c += 8) {
    uint4 raw = *(const uint4*)(xp + c);
    unpack8(raw, x + c);
  }
  float s = 0.f, s2 = 0.f;
#pragma unroll
  for (int q = 0; q < C; q++) { s += x[q]; s2 = fmaf(x[q], x[q], s2); }
#pragma unroll
  for (int off = 32; off >= 1; off >>= 1) { s += __shfl_xor(s, off); s2 += __shfl_xor(s2, off); }
  const float mu = s / D;
  const float rs = rsqrtf(s2 / D - mu * mu + 1e-5f);
  const float* gp = g + lane * C;
  const float* bp = bta + lane * C;
#pragma unroll
  for (int c = 0; c < C; c += 8) {
    float4 g0 = *(const float4*)(gp + c), g1 = *(const float4*)(gp + c + 4);
    float4 t0 = *(const float4*)(bp + c), t1 = *(const float4*)(bp + c + 4);
    float y0 = fmaxf(fmaf((x[c + 0] - mu) * rs, g0.x, t0.x), 0.f);
    float y1 = fmaxf(fmaf((x[c + 1] - mu) * rs, g0.y, t0.y), 0.f);
    float y2 = fmaxf(fmaf((x[c + 2] - mu) * rs, g0.z, t0.z), 0.f);
    float y3 = fmaxf(fmaf((x[c + 3] - mu) * rs, g0.w, t0.w), 0.f);
    float y4 = fmaxf(fmaf((x[c + 4] - mu) * rs, g1.x, t1.x), 0.f);
    float y5 = fmaxf(fmaf((x[c + 5] - mu) * rs, g1.y, t1.y), 0.f);
    float y6 = fmaxf(fmaf((x[c + 6] - mu) * rs, g1.z, t1.z), 0.f);
    float y7 = fmaxf(fmaf((x[c + 7] - mu) * rs, g1.w, t1.w), 0.f);
    uint4 u;
    u.x = pack2(y0, y1); u.y = pack2(y2, y3);
    u.z = pack2(y4, y5); u.w = pack2(y6, y7);
    *(uint4*)(xp + c) = u;
  }
}

// ---- pair-XCD swizzle: bn-siblings (bid=2k,2k+1) land on the SAME XCD ----
static __device__ __forceinline__ int pair_swz(int bid, int nwg) {
  const int cpx2 = nwg >> 4;                 // pairs per XCD
  const int pr = bid >> 1, q = bid & 1;
  return (((pr & 7) * cpx2) + (pr >> 3)) * 2 + q;
}

// ---- 128x256 ring-2 GEMM, all-gload_lds staging, halved acc (R16-proven) ----
// MODE 0: A plain bf16 [M][ldaE]. MODE 2: A per-lane gathered pair rows.
template<int MODE>
__global__ __launch_bounds__(512, 4)
void gemm128x256g(const unsigned short* __restrict__ A, int ldaE,
                  const unsigned short* __restrict__ Bt, int Ktot,
                  const float* __restrict__ bias,
                  unsigned short* __restrict__ C, int ldcE, int ccol0,
                  int NS, int NBN,
                  const int* __restrict__ pidx,
                  const unsigned short* __restrict__ nodeFb,
                  const unsigned short* __restrict__ zsrc) {
  __shared__ __align__(16) unsigned char smem[49152];   // A 2x8K | B 2x16K @16K
  const int tid = threadIdx.x;
  const int lane = tid & 63, w = tid >> 6;
  const int swz = pair_swz(blockIdx.x, gridDim.x);
  const int bm = swz / NBN, bn = swz - bm * NBN;

  const int sslot = (tid & 3) ^ ((tid >> 3) & 3);       // pre-swizzled source k-slot
  const int srow = tid >> 2;                            // 0..127
  const size_t ldaBy = (size_t)ldaE * 2, ldbBy = (size_t)Ktot * 2;
  const unsigned char* aG = (const unsigned char*)A + (size_t)(bm * 128 + srow) * ldaBy + sslot * 16;
  const unsigned char* bG = (const unsigned char*)Bt + (size_t)(bn * 256 + srow) * ldbBy + sslot * 16;

  const unsigned short* nbS = nullptr;
  const unsigned short* nbO = nullptr;
  if (MODE == 2) {
    int pr = bm * 128 + srow;
    int2 so = *(const int2*)(pidx + 2 * pr);
    int b = pr >> 12;
    nbS = nodeFb + (size_t)((b << 7) + so.x) * NODEF;
    nbO = nodeFb + (size_t)((b << 7) + so.y) * NODEF;
  }

  auto stage = [&](int s) {
    const int slot = s & 1;
    unsigned char* la = smem + slot * 8192 + w * 1024;
    unsigned char* lb = smem + 16384 + slot * 16384 + w * 1024;
    if (MODE == 0) {
      async_copy16(aG + (size_t)s * 64, la);
    } else {
      const int e = s * 32 + sslot * 8;
      uintptr_t sel = (e < NODEF) ? (uintptr_t)(nbS + e)
                    : (e < KGEO)  ? (uintptr_t)(nbO + (e - NODEF))
                                  : (uintptr_t)zsrc;
      async_copy16((const void*)sel, la);
    }
    const unsigned char* sb = bG + (size_t)s * 64;
    async_copy16(sb, lb);
    async_copy16(sb + 128 * ldbBy, lb + 8192);
  };

  const int wm = w >> 2, wn = w & 3;                    // 2M x 4N waves, 64x64 each
  const int frow = lane & 15;
  const int colb = (((lane >> 4) ^ ((frow >> 1) & 3)) << 4);
  const int aRowB = (wm * 64 + frow) * 64;
  const int bRowB = (wn * 64 + frow) * 64;

  f32x4 acc[4][4];
#pragma unroll
  for (int m = 0; m < 4; m++)
#pragma unroll
    for (int n = 0; n < 4; n++) acc[m][n] = (f32x4){0.f, 0.f, 0.f, 0.f};

  stage(0); stage(1);
#pragma unroll 1
  for (int s = 0; s < NS; ++s) {
    if (s == NS - 1) asm volatile("s_waitcnt vmcnt(0)" ::: "memory");
    else             asm volatile("s_waitcnt vmcnt(3)" ::: "memory");
    __builtin_amdgcn_s_barrier();
    __builtin_amdgcn_sched_barrier(0);
    const unsigned char* ab = smem + (s & 1) * 8192;
    const unsigned char* bb = smem + 16384 + (s & 1) * 16384;
    bf16x8 af[4];
#pragma unroll
    for (int m = 0; m < 4; m++) af[m] = *(const bf16x8*)(ab + aRowB + m * 1024 + colb);
    __builtin_amdgcn_s_setprio(1);
#pragma unroll
    for (int n = 0; n < 4; n++) {
      bf16x8 bf = *(const bf16x8*)(bb + bRowB + n * 1024 + colb);
#pragma unroll
      for (int m = 0; m < 4; m++)
        acc[m][n] = __builtin_amdgcn_mfma_f32_16x16x32_bf16(af[m], bf, acc[m][n], 0, 0, 0);
    }
    __builtin_amdgcn_s_setprio(0);
    __builtin_amdgcn_sched_barrier(0);
    __builtin_amdgcn_s_barrier();               // readers of slot s&1 done
    __builtin_amdgcn_sched_barrier(0);
    if (s + 2 < NS) stage(s + 2);               // overwrites slot s&1 safely
  }
  const int rb = bm * 128 + wm * 64 + ((lane >> 4) << 2);
  const int cb = bn * 256 + wn * 64 + frow;
#pragma unroll
  for (int n = 0; n < 4; n++) {
    const int col = cb + n * 16;
    const float bv = bias[col];
#pragma unroll
    for (int m = 0; m < 4; m++)
#pragma unroll
      for (int i = 0; i < 4; i++) {
        const int row = rb + m * 16 + i;
        C[(size_t)row * ldcE + ccol0 + col] = f2b(acc[m][n][i] + bv);
      }
  }
}

// ---- 128x256 ring-2 GEMM, A f32+relu+cvt reg-staged, halved acc (R15-proven) ----
__global__ __launch_bounds__(512, 4)
void gemm256f3(const float* __restrict__ A,            // f32, lda = 1024
               const unsigned short* __restrict__ Bt,  // [512][1024] bf16
               const float* __restrict__ bias,
               unsigned short* __restrict__ C, int ldcE, int ccol0,
               int NBN) {
  constexpr int NS = 32;                               // K=1024 / BK=32
  __shared__ __align__(16) unsigned char smem[49152];  // A 2x8K | B 2x16K @16K
  const int tid = threadIdx.x;
  const int lane = tid & 63, w = tid >> 6;
  const int swz = pair_swz(blockIdx.x, gridDim.x);
  const int bm = swz / NBN, bn = swz - bm * NBN;       // bm 0..511, bn 0..1

  const int sslot = (tid & 3) ^ ((tid >> 3) & 3);      // source k-slot (pre-swizzle)
  const int srow = tid >> 2;                           // 0..127
  const float* aG = A + (size_t)(bm * 128 + srow) * 1024 + sslot * 8;
  const unsigned char* bG = (const unsigned char*)Bt + (size_t)(bn * 256 + srow) * 2048 + sslot * 16;
  unsigned char* laBase = smem + srow * 64 + (tid & 3) * 16;
  unsigned char* lbBase = smem + 16384 + w * 1024;

  uint4 ra0[2], ra1[2];                                // 2 static reg sets

  auto issueA = [&](int s, uint4* ra) {
    const float* p0 = aG + (size_t)s * 32;
    ra[0] = *(const uint4*)(p0);
    ra[1] = *(const uint4*)(p0 + 4);
  };
  auto issueB = [&](int s) {
    const int slot = s & 1;
    const unsigned char* sb = bG + (size_t)s * 64;
    async_copy16(sb, lbBase + slot * 16384);
    async_copy16(sb + 128 * 2048, lbBase + slot * 16384 + 8192);
  };
  auto writeA = [&](int s, const uint4* ra) {
    const int slot = s & 1;
    float x0 = fmaxf(__uint_as_float(ra[0].x), 0.f);
    float x1 = fmaxf(__uint_as_float(ra[0].y), 0.f);
    float x2 = fmaxf(__uint_as_float(ra[0].z), 0.f);
    float x3 = fmaxf(__uint_as_float(ra[0].w), 0.f);
    float x4 = fmaxf(__uint_as_float(ra[1].x), 0.f);
    float x5 = fmaxf(__uint_as_float(ra[1].y), 0.f);
    float x6 = fmaxf(__uint_as_float(ra[1].z), 0.f);
    float x7 = fmaxf(__uint_as_float(ra[1].w), 0.f);
    uint4 u;
    u.x = pack2(x0, x1); u.y = pack2(x2, x3);
    u.z = pack2(x4, x5); u.w = pack2(x6, x7);
    *(uint4*)(laBase + slot * 8192) = u;
  };

  const int wm = w >> 2, wn = w & 3;                   // 2M x 4N waves, 64x64 each
  const int frow = lane & 15;
  const int colb = (((lane >> 4) ^ ((frow >> 1) & 3)) << 4);
  const int aRowB = (wm * 64 + frow) * 64;
  const int bRowB = (wn * 64 + frow) * 64;

  f32x4 acc[4][4];
#pragma unroll
  for (int m = 0; m < 4; m++)
#pragma unroll
    for (int n = 0; n < 4; n++) acc[m][n] = (f32x4){0.f, 0.f, 0.f, 0.f};

  issueA(0, ra0); issueB(0);
  issueA(1, ra1); issueB(1);

#pragma unroll 1
  for (int s = 0; s < NS; s += 2) {
#pragma unroll
    for (int half = 0; half < 2; half++) {
      const int sc = s + half;
      uint4* raC = half ? ra1 : ra0;
      if (sc == NS - 1) asm volatile("s_waitcnt vmcnt(0)" ::: "memory");
      else              asm volatile("s_waitcnt vmcnt(4)" ::: "memory");
      __builtin_amdgcn_sched_barrier(0);
      writeA(sc, raC);                       // slot sc&1: readers done at sc-2
      if (sc + 2 < NS) issueA(sc + 2, raC);  // regs only — safe before barrier
      asm volatile("s_waitcnt lgkmcnt(0)" ::: "memory");
      __builtin_amdgcn_s_barrier();
      __builtin_amdgcn_sched_barrier(0);
      const unsigned char* ab = smem + (sc & 1) * 8192;
      const unsigned char* bb = smem + 16384 + (sc & 1) * 16384;
      bf16x8 af[4];
#pragma unroll
      for (int m = 0; m < 4; m++) af[m] = *(const bf16x8*)(ab + aRowB + m * 1024 + colb);
      __builtin_amdgcn_s_setprio(1);
#pragma unroll
      for (int n = 0; n < 4; n++) {
        bf16x8 bf = *(const bf16x8*)(bb + bRowB + n * 1024 + colb);
#pragma unroll
        for (int m = 0; m < 4; m++)
          acc[m][n] = __builtin_amdgcn_mfma_f32_16x16x32_bf16(af[m], bf, acc[m][n], 0, 0, 0);
      }
      __builtin_amdgcn_s_setprio(0);
      __builtin_amdgcn_sched_barrier(0);
      __builtin_amdgcn_s_barrier();          // readers of B slot sc&1 done
      __builtin_amdgcn_sched_barrier(0);
      if (sc + 2 < NS) issueB(sc + 2);       // overwrites B slot sc&1 safely
    }
  }
  const int rb = bm * 128 + wm * 64 + ((lane >> 4) << 2);
  const int cb = bn * 256 + wn * 64 + frow;
#pragma unroll
  for (int n = 0; n < 4; n++) {
    const int col = cb + n * 16;
    const float bv = bias[col];
#pragma unroll
    for (int m = 0; m < 4; m++)
#pragma unroll
      for (int i = 0; i < 4; i++) {
        const int row = rb + m * 16 + i;
        C[(size_t)row * ldcE + ccol0 + col] = f2b(acc[m][n][i] + bv);
      }
  }
}

// ---- 128x256 ring-2 GEMM with FUSED LayerNorm+ReLU on reg-staged A (fus layer) ----
// A bf16 [M][1024] (un-normalized), per-row stats (mu,rs) precomputed; gamma/beta
// staged to LDS once at kernel start (gload_lds + vmcnt(0)+barrier prologue).
// Per stage: 1 A uint4 (reg) + 2 B gload_lds = 3 vm events. Ring-2 ledger:
//   head of phase s: newer-than-{A(s),B(s)} = {A(s+1),B(s+1)x2} = 3 -> vmcnt(3);
//   s==NS-1 -> vmcnt(0) (R3 bug class).
// LDS: A 2x8K | B 2x16K @16K | g 4K @49152 | beta 4K @53248 = 56 KB (2 blocks/CU).
__global__ __launch_bounds__(512, 4)
void gemm_fusLN(const unsigned short* __restrict__ A,   // fused bf16 [M][1024]
                const unsigned short* __restrict__ Bt,  // wT_fus [512][1024]
                const float* __restrict__ stats,        // [M] float2 (mu, rs)
                const float* __restrict__ lng, const float* __restrict__ lnb,
                const float* __restrict__ bias,
                unsigned short* __restrict__ C,         // fused2 [M][512]
                int NBN) {
  constexpr int NS = 32;                                // K=1024 / BK=32
  __shared__ __align__(16) unsigned char smem[57344];
  const int tid = threadIdx.x;
  const int lane = tid & 63, w = tid >> 6;
  const int swz = pair_swz(blockIdx.x, gridDim.x);
  const int bm = swz / NBN, bn = swz - bm * NBN;

  const int sslot = (tid & 3) ^ ((tid >> 3) & 3);
  const int srow = tid >> 2;                            // 0..127, one row per thread
  const unsigned short* aG = A + (size_t)(bm * 128 + srow) * 1024 + sslot * 8;
  const unsigned char* bG = (const unsigned char*)Bt + (size_t)(bn * 256 + srow) * 2048 + sslot * 16;
  unsigned char* laBase = smem + srow * 64 + (tid & 3) * 16;
  unsigned char* lbBase = smem + 16384 + w * 1024;

  // stage gamma (4 KB) / beta (4 KB) into LDS once; then drain+barrier.
  {
    const float* src = (w < 4) ? (lng + w * 256 + lane * 4)
                               : (lnb + (w - 4) * 256 + lane * 4);
    unsigned char* dst = smem + 49152 + w * 4096 / 4;   // w*1024: waves 0-3 -> g, 4-7 -> beta
    async_copy16(src, dst);
  }
  asm volatile("s_waitcnt vmcnt(0)" ::: "memory");
  __builtin_amdgcn_s_barrier();

  const float2 st = ((const float2*)stats)[bm * 128 + srow];
  const float mu = st.x, rs = st.y;
  const float* gl = (const float*)(smem + 49152);
  const float* bl = (const float*)(smem + 53248);

  uint4 ra0, ra1;

  auto issueA = [&](int s, uint4* ra) {
    *ra = *(const uint4*)(aG + (size_t)s * 32);
  };
  auto issueB = [&](int s) {
    const int slot = s & 1;
    const unsigned char* sb = bG + (size_t)s * 64;
    async_copy16(sb, lbBase + slot * 16384);
    async_copy16(sb + 128 * 2048, lbBase + slot * 16384 + 8192);
  };
  auto writeA = [&](int s, const uint4* ra) {
    const int slot = s & 1;
    const int k0 = s * 32 + sslot * 8;
    float x[8]; unpack8(*ra, x);
    float4 g0 = *(const float4*)(gl + k0), g1 = *(const float4*)(gl + k0 + 4);
    float4 t0 = *(const float4*)(bl + k0), t1 = *(const float4*)(bl + k0 + 4);
    float y0 = fmaxf(fmaf((x[0] - mu) * rs, g0.x, t0.x), 0.f);
    float y1 = fmaxf(fmaf((x[1] - mu) * rs, g0.y, t0.y), 0.f);
    float y2 = fmaxf(fmaf((x[2] - mu) * rs, g0.z, t0.z), 0.f);
    float y3 = fmaxf(fmaf((x[3] - mu) * rs, g0.w, t0.w), 0.f);
    float y4 = fmaxf(fmaf((x[4] - mu) * rs, g1.x, t1.x), 0.f);
    float y5 = fmaxf(fmaf((x[5] - mu) * rs, g1.y, t1.y), 0.f);
    float y6 = fmaxf(fmaf((x[6] - mu) * rs, g1.z, t1.z), 0.f);
    float y7 = fmaxf(fmaf((x[7] - mu) * rs, g1.w, t1.w), 0.f);
    uint4 u;
    u.x = pack2(y0, y1); u.y = pack2(y2, y3);
    u.z = pack2(y4, y5); u.w = pack2(y6, y7);
    *(uint4*)(laBase + slot * 8192) = u;
  };

  const int wm = w >> 2, wn = w & 3;
  const int frow = lane & 15;
  const int colb = (((lane >> 4) ^ ((frow >> 1) & 3)) << 4);
  const int aRowB = (wm * 64 + frow) * 64;
  const int bRowB = (wn * 64 + frow) * 64;

  f32x4 acc[4][4];
#pragma unroll
  for (int m = 0; m < 4; m++)
#pragma unroll
    for (int n = 0; n < 4; n++) acc[m][n] = (f32x4){0.f, 0.f, 0.f, 0.f};

  issueA(0, &ra0); issueB(0);
  issueA(1, &ra1); issueB(1);

#pragma unroll 1
  for (int s = 0; s < NS; s += 2) {
#pragma unroll
    for (int half = 0; half < 2; half++) {
      const int sc = s + half;
      uint4* raC = half ? &ra1 : &ra0;
      if (sc == NS - 1) asm volatile("s_waitcnt vmcnt(0)" ::: "memory");
      else              asm volatile("s_waitcnt vmcnt(3)" ::: "memory");
      __builtin_amdgcn_sched_barrier(0);
      writeA(sc, raC);                       // slot sc&1: readers done at sc-2
      if (sc + 2 < NS) issueA(sc + 2, raC);  // reg load — safe before barrier
      asm volatile("s_waitcnt lgkmcnt(0)" ::: "memory");
      __builtin_amdgcn_s_barrier();
      __builtin_amdgcn_sched_barrier(0);
      const unsigned char* ab = smem + (sc & 1) * 8192;
      const unsigned char* bb = smem + 16384 + (sc & 1) * 16384;
      bf16x8 af[4];
#pragma unroll
      for (int m = 0; m < 4; m++) af[m] = *(const bf16x8*)(ab + aRowB + m * 1024 + colb);
      __builtin_amdgcn_s_setprio(1);
#pragma unroll
      for (int n = 0; n < 4; n++) {
        bf16x8 bf = *(const bf16x8*)(bb + bRowB + n * 1024 + colb);
#pragma unroll
        for (int m = 0; m < 4; m++)
          acc[m][n] = __builtin_amdgcn_mfma_f32_16x16x32_bf16(af[m], bf, acc[m][n], 0, 0, 0);
      }
      __builtin_amdgcn_s_setprio(0);
      __builtin_amdgcn_sched_barrier(0);
      __builtin_amdgcn_s_barrier();          // readers of B slot sc&1 done
      __builtin_amdgcn_sched_barrier(0);
      if (sc + 2 < NS) issueB(sc + 2);       // overwrites B slot sc&1 safely
    }
  }
  const int rb = bm * 128 + wm * 64 + ((lane >> 4) << 2);
  const int cb = bn * 256 + wn * 64 + frow;
#pragma unroll
  for (int n = 0; n < 4; n++) {
    const int col = cb + n * 16;
    const float bv = bias[col];
#pragma unroll
    for (int m = 0; m < 4; m++)
#pragma unroll
      for (int i = 0; i < 4; i++) {
        const int row = rb + m * 16 + i;
        C[(size_t)row * 512 + col] = f2b(acc[m][n][i] + bv);
      }
  }
}

// ---- 128x128 m97-structure GEMM for cls layer (N=50) + fused score scatter ----
__global__ __launch_bounds__(256)
void gemm_cls(const unsigned short* __restrict__ A, int lda,
              const unsigned short* __restrict__ Bt,
              const float* __restrict__ bias,
              float* __restrict__ C,
              int Ktot,
              const int* __restrict__ pidx,
              unsigned long long* __restrict__ scat) {
  __shared__ unsigned short ldsA[128 * 64];
  __shared__ unsigned short ldsB[128 * 64];
  const int tid = threadIdx.x;
  const int lane = tid & 63, wid = tid >> 6;
  const int cpx = gridDim.x >> 3;
  const int bm = (blockIdx.x & 7) * cpx + (blockIdx.x >> 3);

  const int srow = wid * 32 + (lane >> 3);
  const int skof = (lane & 7) * 8;
  const unsigned short* ag = A + (size_t)(bm * 128 + srow) * lda + skof;
  const unsigned short* bg = Bt + (size_t)srow * Ktot + skof;

  f32x4 acc[4][4];
#pragma unroll
  for (int m = 0; m < 4; m++)
#pragma unroll
    for (int n = 0; n < 4; n++) acc[m][n] = (f32x4){0.f, 0.f, 0.f, 0.f};

  const int wm = wid >> 1, wn = wid & 1;
  const int frow = lane & 15;
  const int kgrp = (lane >> 4) << 3;

  for (int kt = 0; kt < Ktot; kt += 64) {
#pragma unroll
    for (int i = 0; i < 4; i++) {
      async_copy16(ag + (size_t)i * 8 * lda + kt, &ldsA[wid * 2048 + i * 512]);
      async_copy16(bg + (size_t)i * 8 * Ktot + kt, &ldsB[wid * 2048 + i * 512]);
    }
    __syncthreads();
#pragma unroll
    for (int kk = 0; kk < 64; kk += 32) {
      bf16x8 af[4], bfr[4];
#pragma unroll
      for (int m = 0; m < 4; m++)
        af[m] = *(const bf16x8*)&ldsA[(wm * 64 + m * 16 + frow) * 64 + kk + kgrp];
#pragma unroll
      for (int n = 0; n < 4; n++)
        bfr[n] = *(const bf16x8*)&ldsB[(wn * 64 + n * 16 + frow) * 64 + kk + kgrp];
#pragma unroll
      for (int m = 0; m < 4; m++)
#pragma unroll
        for (int n = 0; n < 4; n++)
          acc[m][n] = __builtin_amdgcn_mfma_f32_16x16x32_bf16(af[m], bfr[n], acc[m][n], 0, 0, 0);
    }
    __syncthreads();
  }
  const int rb = bm * 128 + wm * 64 + ((lane >> 4) << 2);
#pragma unroll
  for (int n = 0; n < 4; n++) {
    const int col = wn * 64 + frow + n * 16;
    const float bv = (col < OUTC) ? bias[col] : 0.f;
#pragma unroll
    for (int m = 0; m < 4; m++)
#pragma unroll
      for (int i = 0; i < 4; i++) {
        const int row = rb + m * 16 + i;
        if (col < OUTC) C[(size_t)row * OUTC + col] = acc[m][n][i] + bv;
      }
  }
  // fused score: wn==0 waves hold cols 0..63 of their 64 rows
  if (wn == 0) {
#pragma unroll
    for (int m = 0; m < 4; m++)
#pragma unroll
      for (int i = 0; i < 4; i++) {
        float mx = -1e30f;
#pragma unroll
        for (int n = 0; n < 4; n++) {
          const int col = n * 16 + frow;
          float v = acc[m][n][i] + ((col < OUTC) ? bias[col] : 0.f);
          if (col < OUTC) mx = fmaxf(mx, v);
        }
        mx = fmaxf(mx, __shfl_xor(mx, 1));
        mx = fmaxf(mx, __shfl_xor(mx, 2));
        mx = fmaxf(mx, __shfl_xor(mx, 4));
        mx = fmaxf(mx, __shfl_xor(mx, 8));
        if (frow == 0) {
          const int row = rb + m * 16 + i;
          float sc = 1.f / (1.f + expf(-mx));
          int b = row >> 12, p = row & 4095;
          int s = pidx[2 * row], o = pidx[2 * row + 1];
          unsigned long long key = (((unsigned long long)(p + 1)) << 32) |
                                   (unsigned long long)__float_as_uint(sc);
          atomicMax(&scat[((size_t)(b * N_ + s) << 7) + o], key);
        }
      }
  }
}

__global__ void relmat_kernel(const unsigned long long* __restrict__ scat, float* __restrict__ out) {
  int i = blockIdx.x * blockDim.x + threadIdx.x;
  if (i >= B_ * N_ * N_) return;
  unsigned long long v = scat[i];
  out[i] = v ? __uint_as_float((unsigned)(v & 0xffffffffu)) : 0.f;
}

extern "C" void kernel_launch(void* const* d_in, const int* in_sizes, int n_in,
                              void* d_out, int out_size, void* d_ws, size_t ws_size,
                              hipStream_t stream) {
  const float* visual_feat = (const float*)d_in[0];
  const float* box_info    = (const float*)d_in[1];
  const float* pred_logits = (const float*)d_in[2];
  const int*   pair_idx    = (const int*)d_in[3];
  const float* obj_sem_w   = (const float*)d_in[4];
  const float* pos_w1 = (const float*)d_in[5];
  const float* pos_b1 = (const float*)d_in[6];
  const float* pos_w2 = (const float*)d_in[7];
  const float* pos_b2 = (const float*)d_in[8];
  const float* vis_w  = (const float*)d_in[9];
  const float* vis_b  = (const float*)d_in[10];
  const float* geo_w  = (const float*)d_in[11];
  const float* geo_b  = (const float*)d_in[12];
  const float* fus_g  = (const float*)d_in[13];
  const float* fus_bt = (const float*)d_in[14];
  const float* fus_w  = (const float*)d_in[15];
  const float* fus_b  = (const float*)d_in[16];
  const float* cls_g  = (const float*)d_in[17];
  const float* cls_bt = (const float*)d_in[18];
  const float* cls_w  = (const float*)d_in[19];
  const float* cls_b  = (const float*)d_in[20];

  char* ws = (char*)d_ws;
  size_t off = 0;
  auto alloc = [&](size_t bytes) { char* p = ws + off; off += (bytes + 255) & ~(size_t)255; return p; };
  unsigned short* fused = (unsigned short*)alloc((size_t)M_ * 1024 * 2);      // 134 MB
  unsigned short* fused2 = (unsigned short*)alloc((size_t)M_ * 512 * 2);      // 67 MB
  unsigned short* nodeFb = (unsigned short*)alloc((size_t)B_ * N_ * NODEF * 2);
  unsigned short* wT_vis = (unsigned short*)alloc((size_t)512 * 1024 * 2);
  unsigned short* wT_geo = (unsigned short*)alloc((size_t)512 * KGEOP * 2);
  unsigned short* wT_fus = (unsigned short*)alloc((size_t)512 * 1024 * 2);
  unsigned short* wT_cls = (unsigned short*)alloc((size_t)128 * 512 * 2);
  unsigned long long* scat = (unsigned long long*)alloc((size_t)B_ * N_ * N_ * 8);
  float* stats1 = (float*)alloc((size_t)M_ * 2 * 4);

  float* out_logits = (float*)d_out;
  float* out_rel = out_logits + (size_t)M_ * OUTC;

  prep_kernel<<<dim3((PREP_TOT + 255) / 256), 256, 0, stream>>>(
      (uint4*)scat, vis_w, wT_vis, geo_w, wT_geo, fus_w, wT_fus, cls_w, wT_cls);
  node_kernel<<<dim3(B_ * N_), 128, 0, stream>>>(box_info, pred_logits, obj_sem_w,
                                                 pos_w1, pos_b1, pos_w2, pos_b2, nodeFb);
  // geo: 128x256 halved-acc gather GEMM -> fused[:,512:]
  gemm128x256g<2><<<dim3(1024), 512, 0, stream>>>(nullptr, 0, wT_geo, KGEOP, geo_b,
                                                  fused, 1024, 512, KGEOP / 32, 2,
                                                  pair_idx, nodeFb, (const unsigned short*)scat);
  // vis: 128x256 halved-acc ring-2 GEMM with fused f32->relu->bf16 (R15-proven)
  gemm256f3<<<dim3(1024), 512, 0, stream>>>(visual_feat, wT_vis, vis_b,
                                            fused, 1024, 0, 2);
  // LN stats for fused rows (mu, rs); LN+relu applied inside the fus GEMM
  stats_kernel<<<dim3(M_ / 4), 256, 0, stream>>>(fused, stats1);
  gemm_fusLN<<<dim3(1024), 512, 0, stream>>>(fused, wT_fus, stats1, fus_g, fus_bt,
                                             fus_b, fused2, 2);
  ln_relu_kernel<512><<<dim3(M_ / 4), 256, 0, stream>>>(fused2, cls_g, cls_bt);
  gemm_cls<<<dim3(512), 256, 0, stream>>>(fused2, 512, wT_cls, cls_b,
                                          out_logits, 512, pair_idx, scat);
  relmat_kernel<<<dim3((B_ * N_ * N_) / 256), 256, 0, stream>>>(scat, out_rel);
}

// Round 18
// 374.429 us; speedup vs baseline: 1.3516x; 1.0312x over previous
//
#include <hip/hip_runtime.h>
#include <cstdint>

#define B_    16
#define N_    128
#define P_    4096
#define M_    65536     // B_*P_
#define DIN   1024
#define DHID  512
#define DGEO  128
#define DEMB  200
#define NODEF 328       // DGEO + DEMB
#define NOBJ  151
#define OUTC  50
#define KGEO  656
#define KGEOP 672       // geo K padded to multiple of 32 (ring BK=32)

typedef __attribute__((ext_vector_type(8))) short bf16x8;
typedef __attribute__((ext_vector_type(4))) float f32x4;

typedef __attribute__((address_space(3))) unsigned char lds_u8;
typedef __attribute__((address_space(1))) unsigned char glb_u8;

static __device__ __forceinline__ void async_copy16(const void* g, void* l) {
  __builtin_amdgcn_global_load_lds((const glb_u8*)g, (lds_u8*)l, 16, 0, 0);
}

static __device__ __forceinline__ unsigned short f2b(float f) {
  union { float f; unsigned u; } v; v.f = f;
  unsigned r = v.u + 0x7fffu + ((v.u >> 16) & 1u);
  return (unsigned short)(r >> 16);
}
static __device__ __forceinline__ float b2f(unsigned short b) {
  union { unsigned u; float f; } v; v.u = ((unsigned)b) << 16;
  return v.f;
}
static __device__ __forceinline__ unsigned pack2(float a, float b) {
  return (unsigned)f2b(a) | ((unsigned)f2b(b) << 16);
}
static __device__ __forceinline__ void unpack8(uint4 raw, float* x) {
  x[0] = b2f(raw.x & 0xffffu); x[1] = b2f(raw.x >> 16);
  x[2] = b2f(raw.y & 0xffffu); x[3] = b2f(raw.y >> 16);
  x[4] = b2f(raw.z & 0xffffu); x[5] = b2f(raw.z >> 16);
  x[6] = b2f(raw.w & 0xffffu); x[7] = b2f(raw.w >> 16);
}

// ---- merged prologue: zero scat + all 4 weight transposes in one launch ----
#define ZN   131072                    // scat zero, uint4 count (2 MB)
#define TV   (512 * 1024)              // wT_vis elems
#define TG   (512 * KGEOP)             // wT_geo elems
#define TF   (512 * 1024)              // wT_fus elems
#define TC   (128 * 512)               // wT_cls elems
#define PREP_TOT (ZN + TV + TG + TF + TC)
__global__ __launch_bounds__(256)
void prep_kernel(uint4* __restrict__ scat,
                 const float* __restrict__ vis_w, unsigned short* __restrict__ wT_vis,
                 const float* __restrict__ geo_w, unsigned short* __restrict__ wT_geo,
                 const float* __restrict__ fus_w, unsigned short* __restrict__ wT_fus,
                 const float* __restrict__ cls_w, unsigned short* __restrict__ wT_cls) {
  int idx = blockIdx.x * 256 + threadIdx.x;
  if (idx < ZN) { scat[idx] = make_uint4(0, 0, 0, 0); return; }
  idx -= ZN;
  if (idx < TV) {
    int n = idx >> 10, k = idx & 1023;
    wT_vis[idx] = f2b(vis_w[(size_t)k * 512 + n]);
    return;
  }
  idx -= TV;
  if (idx < TG) {
    int n = idx / KGEOP, k = idx - n * KGEOP;
    wT_geo[idx] = (k < KGEO) ? f2b(geo_w[(size_t)k * 512 + n]) : 0;
    return;
  }
  idx -= TG;
  if (idx < TF) {
    int n = idx >> 10, k = idx & 1023;
    wT_fus[idx] = f2b(fus_w[(size_t)k * 512 + n]);
    return;
  }
  idx -= TF;
  if (idx < TC) {
    int n = idx >> 9, k = idx & 511;
    wT_cls[idx] = (n < OUTC) ? f2b(cls_w[(size_t)k * OUTC + n]) : 0;
  }
}

// ---- per-node features (relu'd, bf16): nodeFb[node] = [relu(pos)(128), relu(sem)(200)] ----
__global__ __launch_bounds__(128)
void node_kernel(const float* __restrict__ box, const float* __restrict__ plog,
                 const float* __restrict__ semw,
                 const float* __restrict__ w1, const float* __restrict__ b1,
                 const float* __restrict__ w2, const float* __restrict__ b2,
                 unsigned short* __restrict__ nodeFb) {
  const int node = blockIdx.x;
  const int t = threadIdx.x;
  __shared__ float sBox[9];
  __shared__ float sH[128];
  __shared__ float sE[NOBJ];
  __shared__ float sRed[4];
  if (t < 9) sBox[t] = box[node * 9 + t];
  float l0 = (t < NOBJ) ? plog[node * NOBJ + t] : -1e30f;
  float l1 = (t + 128 < NOBJ) ? plog[node * NOBJ + t + 128] : -1e30f;
  __syncthreads();
  float h = b1[t];
#pragma unroll
  for (int i = 0; i < 9; i++) h = fmaf(sBox[i], w1[i * 128 + t], h);
  h = fmaxf(h, 0.f);
  sH[t] = h;
  float mx = fmaxf(l0, l1);
#pragma unroll
  for (int off = 32; off >= 1; off >>= 1) mx = fmaxf(mx, __shfl_xor(mx, off));
  if ((t & 63) == 0) sRed[t >> 6] = mx;
  __syncthreads();
  mx = fmaxf(sRed[0], sRed[1]);
  float e0 = (t < NOBJ) ? expf(l0 - mx) : 0.f;
  float e1 = (t + 128 < NOBJ) ? expf(l1 - mx) : 0.f;
  if (t < NOBJ) sE[t] = e0;
  if (t + 128 < NOBJ) sE[t + 128] = e1;
  float sm = e0 + e1;
#pragma unroll
  for (int off = 32; off >= 1; off >>= 1) sm += __shfl_xor(sm, off);
  if ((t & 63) == 0) sRed[2 + (t >> 6)] = sm;
  __syncthreads();
  const float inv = 1.f / (sRed[2] + sRed[3]);
  float pv = b2[t];
  for (int i = 0; i < 128; i++) pv = fmaf(sH[i], w2[i * 128 + t], pv);
  nodeFb[(size_t)node * NODEF + t] = f2b(fmaxf(pv, 0.f));
  float a0 = 0.f, a1 = 0.f;
  const int d1 = (t + 128 < DEMB) ? (t + 128) : 0;
  for (int i = 0; i < NOBJ; i++) {
    float e = sE[i];
    a0 = fmaf(e, semw[i * DEMB + t], a0);
    a1 = fmaf(e, semw[i * DEMB + d1], a1);
  }
  nodeFb[(size_t)node * NODEF + 128 + t] = f2b(fmaxf(a0 * inv, 0.f));
  if (t + 128 < DEMB) nodeFb[(size_t)node * NODEF + 128 + t + 128] = f2b(fmaxf(a1 * inv, 0.f));
}

// ---- pair-XCD swizzle: bn-siblings (bid=2k,2k+1) land on the SAME XCD ----
static __device__ __forceinline__ int pair_swz(int bid, int nwg) {
  const int cpx2 = nwg >> 4;                 // pairs per XCD
  const int pr = bid >> 1, q = bid & 1;
  return (((pr & 7) * cpx2) + (pr >> 3)) * 2 + q;
}

// ---- 128x256 ring-2 GEMM, all-gload_lds staging (geo gather) + row-stats out ----
// Stats: per wave, per row: (sum, sumsq) over its 64 cols -> statsOut[row*16 + 8+bn*4+wn]
// (deterministic per-slot writes; fixed-order combine in consumer).
__global__ __launch_bounds__(512, 4)
void gemm_geo(const unsigned short* __restrict__ Bt, int Ktot,
              const float* __restrict__ bias,
              unsigned short* __restrict__ C, int ldcE, int ccol0,
              int NS, int NBN,
              const int* __restrict__ pidx,
              const unsigned short* __restrict__ nodeFb,
              const unsigned short* __restrict__ zsrc,
              float2* __restrict__ statsOut) {
  __shared__ __align__(16) unsigned char smem[49152];   // A 2x8K | B 2x16K @16K
  const int tid = threadIdx.x;
  const int lane = tid & 63, w = tid >> 6;
  const int swz = pair_swz(blockIdx.x, gridDim.x);
  const int bm = swz / NBN, bn = swz - bm * NBN;

  const int sslot = (tid & 3) ^ ((tid >> 3) & 3);       // pre-swizzled source k-slot
  const int srow = tid >> 2;                            // 0..127
  const size_t ldbBy = (size_t)Ktot * 2;
  const unsigned char* bG = (const unsigned char*)Bt + (size_t)(bn * 256 + srow) * ldbBy + sslot * 16;

  int pr = bm * 128 + srow;
  int2 so = *(const int2*)(pidx + 2 * pr);
  int b = pr >> 12;
  const unsigned short* nbS = nodeFb + (size_t)((b << 7) + so.x) * NODEF;
  const unsigned short* nbO = nodeFb + (size_t)((b << 7) + so.y) * NODEF;

  auto stage = [&](int s) {
    const int slot = s & 1;
    unsigned char* la = smem + slot * 8192 + w * 1024;
    unsigned char* lb = smem + 16384 + slot * 16384 + w * 1024;
    const int e = s * 32 + sslot * 8;
    uintptr_t sel = (e < NODEF) ? (uintptr_t)(nbS + e)
                  : (e < KGEO)  ? (uintptr_t)(nbO + (e - NODEF))
                                : (uintptr_t)zsrc;
    async_copy16((const void*)sel, la);
    const unsigned char* sb = bG + (size_t)s * 64;
    async_copy16(sb, lb);
    async_copy16(sb + 128 * ldbBy, lb + 8192);
  };

  const int wm = w >> 2, wn = w & 3;                    // 2M x 4N waves, 64x64 each
  const int frow = lane & 15;
  const int colb = (((lane >> 4) ^ ((frow >> 1) & 3)) << 4);
  const int aRowB = (wm * 64 + frow) * 64;
  const int bRowB = (wn * 64 + frow) * 64;

  f32x4 acc[4][4];
#pragma unroll
  for (int m = 0; m < 4; m++)
#pragma unroll
    for (int n = 0; n < 4; n++) acc[m][n] = (f32x4){0.f, 0.f, 0.f, 0.f};

  stage(0); stage(1);
#pragma unroll 1
  for (int s = 0; s < NS; ++s) {
    if (s == NS - 1) asm volatile("s_waitcnt vmcnt(0)" ::: "memory");
    else             asm volatile("s_waitcnt vmcnt(3)" ::: "memory");
    __builtin_amdgcn_s_barrier();
    __builtin_amdgcn_sched_barrier(0);
    const unsigned char* ab = smem + (s & 1) * 8192;
    const unsigned char* bb = smem + 16384 + (s & 1) * 16384;
    bf16x8 af[4];
#pragma unroll
    for (int m = 0; m < 4; m++) af[m] = *(const bf16x8*)(ab + aRowB + m * 1024 + colb);
    __builtin_amdgcn_s_setprio(1);
#pragma unroll
    for (int n = 0; n < 4; n++) {
      bf16x8 bf = *(const bf16x8*)(bb + bRowB + n * 1024 + colb);
#pragma unroll
      for (int m = 0; m < 4; m++)
        acc[m][n] = __builtin_amdgcn_mfma_f32_16x16x32_bf16(af[m], bf, acc[m][n], 0, 0, 0);
    }
    __builtin_amdgcn_s_setprio(0);
    __builtin_amdgcn_sched_barrier(0);
    __builtin_amdgcn_s_barrier();
    __builtin_amdgcn_sched_barrier(0);
    if (s + 2 < NS) stage(s + 2);
  }
  const int rb = bm * 128 + wm * 64 + ((lane >> 4) << 2);
  const int cb = bn * 256 + wn * 64 + frow;
  float bv[4];
#pragma unroll
  for (int n = 0; n < 4; n++) bv[n] = bias[cb + n * 16];
#pragma unroll
  for (int n = 0; n < 4; n++) {
    const int col = cb + n * 16;
#pragma unroll
    for (int m = 0; m < 4; m++)
#pragma unroll
      for (int i = 0; i < 4; i++)
        C[(size_t)(rb + m * 16 + i) * ldcE + ccol0 + col] = f2b(acc[m][n][i] + bv[n]);
  }
  const int slot = 8 + bn * 4 + wn;
#pragma unroll
  for (int m = 0; m < 4; m++)
#pragma unroll
    for (int i = 0; i < 4; i++) {
      float s = 0.f, s2 = 0.f;
#pragma unroll
      for (int n = 0; n < 4; n++) {
        float v = acc[m][n][i] + bv[n];
        s += v; s2 = fmaf(v, v, s2);
      }
#pragma unroll
      for (int off = 1; off <= 8; off <<= 1) { s += __shfl_xor(s, off); s2 += __shfl_xor(s2, off); }
      if (frow == 0) statsOut[(size_t)(rb + m * 16 + i) * 16 + slot] = make_float2(s, s2);
    }
}

// ---- 128x256 ring-2 GEMM, A f32+relu+cvt reg-staged (vis) + row-stats out ----
__global__ __launch_bounds__(512, 4)
void gemm256f3(const float* __restrict__ A,            // f32, lda = 1024
               const unsigned short* __restrict__ Bt,  // [512][1024] bf16
               const float* __restrict__ bias,
               unsigned short* __restrict__ C, int ldcE, int ccol0,
               int NBN, float2* __restrict__ statsOut) {
  constexpr int NS = 32;                               // K=1024 / BK=32
  __shared__ __align__(16) unsigned char smem[49152];  // A 2x8K | B 2x16K @16K
  const int tid = threadIdx.x;
  const int lane = tid & 63, w = tid >> 6;
  const int swz = pair_swz(blockIdx.x, gridDim.x);
  const int bm = swz / NBN, bn = swz - bm * NBN;

  const int sslot = (tid & 3) ^ ((tid >> 3) & 3);
  const int srow = tid >> 2;
  const float* aG = A + (size_t)(bm * 128 + srow) * 1024 + sslot * 8;
  const unsigned char* bG = (const unsigned char*)Bt + (size_t)(bn * 256 + srow) * 2048 + sslot * 16;
  unsigned char* laBase = smem + srow * 64 + (tid & 3) * 16;
  unsigned char* lbBase = smem + 16384 + w * 1024;

  uint4 ra0[2], ra1[2];

  auto issueA = [&](int s, uint4* ra) {
    const float* p0 = aG + (size_t)s * 32;
    ra[0] = *(const uint4*)(p0);
    ra[1] = *(const uint4*)(p0 + 4);
  };
  auto issueB = [&](int s) {
    const int slot = s & 1;
    const unsigned char* sb = bG + (size_t)s * 64;
    async_copy16(sb, lbBase + slot * 16384);
    async_copy16(sb + 128 * 2048, lbBase + slot * 16384 + 8192);
  };
  auto writeA = [&](int s, const uint4* ra) {
    const int slot = s & 1;
    float x0 = fmaxf(__uint_as_float(ra[0].x), 0.f);
    float x1 = fmaxf(__uint_as_float(ra[0].y), 0.f);
    float x2 = fmaxf(__uint_as_float(ra[0].z), 0.f);
    float x3 = fmaxf(__uint_as_float(ra[0].w), 0.f);
    float x4 = fmaxf(__uint_as_float(ra[1].x), 0.f);
    float x5 = fmaxf(__uint_as_float(ra[1].y), 0.f);
    float x6 = fmaxf(__uint_as_float(ra[1].z), 0.f);
    float x7 = fmaxf(__uint_as_float(ra[1].w), 0.f);
    uint4 u;
    u.x = pack2(x0, x1); u.y = pack2(x2, x3);
    u.z = pack2(x4, x5); u.w = pack2(x6, x7);
    *(uint4*)(laBase + slot * 8192) = u;
  };

  const int wm = w >> 2, wn = w & 3;
  const int frow = lane & 15;
  const int colb = (((lane >> 4) ^ ((frow >> 1) & 3)) << 4);
  const int aRowB = (wm * 64 + frow) * 64;
  const int bRowB = (wn * 64 + frow) * 64;

  f32x4 acc[4][4];
#pragma unroll
  for (int m = 0; m < 4; m++)
#pragma unroll
    for (int n = 0; n < 4; n++) acc[m][n] = (f32x4){0.f, 0.f, 0.f, 0.f};

  issueA(0, ra0); issueB(0);
  issueA(1, ra1); issueB(1);

#pragma unroll 1
  for (int s = 0; s < NS; s += 2) {
#pragma unroll
    for (int half = 0; half < 2; half++) {
      const int sc = s + half;
      uint4* raC = half ? ra1 : ra0;
      if (sc == NS - 1) asm volatile("s_waitcnt vmcnt(0)" ::: "memory");
      else              asm volatile("s_waitcnt vmcnt(4)" ::: "memory");
      __builtin_amdgcn_sched_barrier(0);
      writeA(sc, raC);
      if (sc + 2 < NS) issueA(sc + 2, raC);
      asm volatile("s_waitcnt lgkmcnt(0)" ::: "memory");
      __builtin_amdgcn_s_barrier();
      __builtin_amdgcn_sched_barrier(0);
      const unsigned char* ab = smem + (sc & 1) * 8192;
      const unsigned char* bb = smem + 16384 + (sc & 1) * 16384;
      bf16x8 af[4];
#pragma unroll
      for (int m = 0; m < 4; m++) af[m] = *(const bf16x8*)(ab + aRowB + m * 1024 + colb);
      __builtin_amdgcn_s_setprio(1);
#pragma unroll
      for (int n = 0; n < 4; n++) {
        bf16x8 bf = *(const bf16x8*)(bb + bRowB + n * 1024 + colb);
#pragma unroll
        for (int m = 0; m < 4; m++)
          acc[m][n] = __builtin_amdgcn_mfma_f32_16x16x32_bf16(af[m], bf, acc[m][n], 0, 0, 0);
      }
      __builtin_amdgcn_s_setprio(0);
      __builtin_amdgcn_sched_barrier(0);
      __builtin_amdgcn_s_barrier();
      __builtin_amdgcn_sched_barrier(0);
      if (sc + 2 < NS) issueB(sc + 2);
    }
  }
  const int rb = bm * 128 + wm * 64 + ((lane >> 4) << 2);
  const int cb = bn * 256 + wn * 64 + frow;
  float bv[4];
#pragma unroll
  for (int n = 0; n < 4; n++) bv[n] = bias[cb + n * 16];
#pragma unroll
  for (int n = 0; n < 4; n++) {
    const int col = cb + n * 16;
#pragma unroll
    for (int m = 0; m < 4; m++)
#pragma unroll
      for (int i = 0; i < 4; i++)
        C[(size_t)(rb + m * 16 + i) * ldcE + ccol0 + col] = f2b(acc[m][n][i] + bv[n]);
  }
  const int slot = bn * 4 + wn;
#pragma unroll
  for (int m = 0; m < 4; m++)
#pragma unroll
    for (int i = 0; i < 4; i++) {
      float s = 0.f, s2 = 0.f;
#pragma unroll
      for (int n = 0; n < 4; n++) {
        float v = acc[m][n][i] + bv[n];
        s += v; s2 = fmaf(v, v, s2);
      }
#pragma unroll
      for (int off = 1; off <= 8; off <<= 1) { s += __shfl_xor(s, off); s2 += __shfl_xor(s2, off); }
      if (frow == 0) statsOut[(size_t)(rb + m * 16 + i) * 16 + slot] = make_float2(s, s2);
    }
}

// ---- 128x256 ring-2 GEMM, FUSED LayerNorm+ReLU A-staging (fus) + stats2 out ----
__global__ __launch_bounds__(512, 4)
void gemm_fusLN(const unsigned short* __restrict__ A,   // fused bf16 [M][1024]
                const unsigned short* __restrict__ Bt,  // wT_fus [512][1024]
                const float2* __restrict__ statsIn,     // [M][16] partial (s,s2)
                const float* __restrict__ lng, const float* __restrict__ lnb,
                const float* __restrict__ bias,
                unsigned short* __restrict__ C,         // fused2 [M][512]
                int NBN, float2* __restrict__ statsOut) {
  constexpr int NS = 32;
  __shared__ __align__(16) unsigned char smem[57344];
  const int tid = threadIdx.x;
  const int lane = tid & 63, w = tid >> 6;
  const int swz = pair_swz(blockIdx.x, gridDim.x);
  const int bm = swz / NBN, bn = swz - bm * NBN;

  const int sslot = (tid & 3) ^ ((tid >> 3) & 3);
  const int srow = tid >> 2;
  const unsigned short* aG = A + (size_t)(bm * 128 + srow) * 1024 + sslot * 8;
  const unsigned char* bG = (const unsigned char*)Bt + (size_t)(bn * 256 + srow) * 2048 + sslot * 16;
  unsigned char* laBase = smem + srow * 64 + (tid & 3) * 16;
  unsigned char* lbBase = smem + 16384 + w * 1024;

  {
    const float* src = (w < 4) ? (lng + w * 256 + lane * 4)
                               : (lnb + (w - 4) * 256 + lane * 4);
    unsigned char* dst = smem + 49152 + w * 1024;
    async_copy16(src, dst);
  }
  asm volatile("s_waitcnt vmcnt(0)" ::: "memory");
  __builtin_amdgcn_s_barrier();

  // fixed-order combine of 16 partial stats -> mu, rs (deterministic)
  float ssum = 0.f, ssq = 0.f;
  {
    const float2* sp = statsIn + (size_t)(bm * 128 + srow) * 16;
#pragma unroll
    for (int j = 0; j < 16; j++) { float2 p = sp[j]; ssum += p.x; ssq += p.y; }
  }
  const float mu = ssum * (1.f / 1024.f);
  const float rs = rsqrtf(ssq * (1.f / 1024.f) - mu * mu + 1e-5f);
  const float* gl = (const float*)(smem + 49152);
  const float* bl = (const float*)(smem + 53248);

  uint4 ra0, ra1;

  auto issueA = [&](int s, uint4* ra) {
    *ra = *(const uint4*)(aG + (size_t)s * 32);
  };
  auto issueB = [&](int s) {
    const int slot = s & 1;
    const unsigned char* sb = bG + (size_t)s * 64;
    async_copy16(sb, lbBase + slot * 16384);
    async_copy16(sb + 128 * 2048, lbBase + slot * 16384 + 8192);
  };
  auto writeA = [&](int s, const uint4* ra) {
    const int slot = s & 1;
    const int k0 = s * 32 + sslot * 8;
    float x[8]; unpack8(*ra, x);
    float4 g0 = *(const float4*)(gl + k0), g1 = *(const float4*)(gl + k0 + 4);
    float4 t0 = *(const float4*)(bl + k0), t1 = *(const float4*)(bl + k0 + 4);
    float y0 = fmaxf(fmaf((x[0] - mu) * rs, g0.x, t0.x), 0.f);
    float y1 = fmaxf(fmaf((x[1] - mu) * rs, g0.y, t0.y), 0.f);
    float y2 = fmaxf(fmaf((x[2] - mu) * rs, g0.z, t0.z), 0.f);
    float y3 = fmaxf(fmaf((x[3] - mu) * rs, g0.w, t0.w), 0.f);
    float y4 = fmaxf(fmaf((x[4] - mu) * rs, g1.x, t1.x), 0.f);
    float y5 = fmaxf(fmaf((x[5] - mu) * rs, g1.y, t1.y), 0.f);
    float y6 = fmaxf(fmaf((x[6] - mu) * rs, g1.z, t1.z), 0.f);
    float y7 = fmaxf(fmaf((x[7] - mu) * rs, g1.w, t1.w), 0.f);
    uint4 u;
    u.x = pack2(y0, y1); u.y = pack2(y2, y3);
    u.z = pack2(y4, y5); u.w = pack2(y6, y7);
    *(uint4*)(laBase + slot * 8192) = u;
  };

  const int wm = w >> 2, wn = w & 3;
  const int frow = lane & 15;
  const int colb = (((lane >> 4) ^ ((frow >> 1) & 3)) << 4);
  const int aRowB = (wm * 64 + frow) * 64;
  const int bRowB = (wn * 64 + frow) * 64;

  f32x4 acc[4][4];
#pragma unroll
  for (int m = 0; m < 4; m++)
#pragma unroll
    for (int n = 0; n < 4; n++) acc[m][n] = (f32x4){0.f, 0.f, 0.f, 0.f};

  issueA(0, &ra0); issueB(0);
  issueA(1, &ra1); issueB(1);

#pragma unroll 1
  for (int s = 0; s < NS; s += 2) {
#pragma unroll
    for (int half = 0; half < 2; half++) {
      const int sc = s + half;
      uint4* raC = half ? &ra1 : &ra0;
      if (sc == NS - 1) asm volatile("s_waitcnt vmcnt(0)" ::: "memory");
      else              asm volatile("s_waitcnt vmcnt(3)" ::: "memory");
      __builtin_amdgcn_sched_barrier(0);
      writeA(sc, raC);
      if (sc + 2 < NS) issueA(sc + 2, raC);
      asm volatile("s_waitcnt lgkmcnt(0)" ::: "memory");
      __builtin_amdgcn_s_barrier();
      __builtin_amdgcn_sched_barrier(0);
      const unsigned char* ab = smem + (sc & 1) * 8192;
      const unsigned char* bb = smem + 16384 + (sc & 1) * 16384;
      bf16x8 af[4];
#pragma unroll
      for (int m = 0; m < 4; m++) af[m] = *(const bf16x8*)(ab + aRowB + m * 1024 + colb);
      __builtin_amdgcn_s_setprio(1);
#pragma unroll
      for (int n = 0; n < 4; n++) {
        bf16x8 bf = *(const bf16x8*)(bb + bRowB + n * 1024 + colb);
#pragma unroll
        for (int m = 0; m < 4; m++)
          acc[m][n] = __builtin_amdgcn_mfma_f32_16x16x32_bf16(af[m], bf, acc[m][n], 0, 0, 0);
      }
      __builtin_amdgcn_s_setprio(0);
      __builtin_amdgcn_sched_barrier(0);
      __builtin_amdgcn_s_barrier();
      __builtin_amdgcn_sched_barrier(0);
      if (sc + 2 < NS) issueB(sc + 2);
    }
  }
  const int rb = bm * 128 + wm * 64 + ((lane >> 4) << 2);
  const int cb = bn * 256 + wn * 64 + frow;
  float bv[4];
#pragma unroll
  for (int n = 0; n < 4; n++) bv[n] = bias[cb + n * 16];
#pragma unroll
  for (int n = 0; n < 4; n++) {
    const int col = cb + n * 16;
#pragma unroll
    for (int m = 0; m < 4; m++)
#pragma unroll
      for (int i = 0; i < 4; i++)
        C[(size_t)(rb + m * 16 + i) * 512 + col] = f2b(acc[m][n][i] + bv[n]);
  }
  const int slot = bn * 4 + wn;
#pragma unroll
  for (int m = 0; m < 4; m++)
#pragma unroll
    for (int i = 0; i < 4; i++) {
      float s = 0.f, s2 = 0.f;
#pragma unroll
      for (int n = 0; n < 4; n++) {
        float v = acc[m][n][i] + bv[n];
        s += v; s2 = fmaf(v, v, s2);
      }
#pragma unroll
      for (int off = 1; off <= 8; off <<= 1) { s += __shfl_xor(s, off); s2 += __shfl_xor(s2, off); }
      if (frow == 0) statsOut[(size_t)(rb + m * 16 + i) * 8 + slot] = make_float2(s, s2);
    }
}

// ---- 128x128 ring-2 cls GEMM with FUSED LN+ReLU A-staging + score scatter ----
// 8 waves 4M x 2N (wave 32x64), acc[2][4]; wn==0 waves hold cols 0..63 (>=50).
// Per stage: 1 A uint4 (reg) + 1 B gload_lds = 2 vm events. Ring-2 ledger:
//   head of phase s: newer-than-{A(s),B(s)} = {A(s+1),B(s+1)} = 2 -> vmcnt(2);
//   s==NS-1 -> vmcnt(0) (R3 bug class). NS = 512/32 = 16.
// LDS: A 2x8K | B 2x8K @16384 | gamma 2K @32768 | beta 2K @34816.
__global__ __launch_bounds__(512, 4)
void gemm_clsLN(const unsigned short* __restrict__ A,   // fused2 bf16 [M][512]
                const unsigned short* __restrict__ Bt,  // wT_cls [128][512]
                const float2* __restrict__ statsIn,     // [M][8] partial (s,s2)
                const float* __restrict__ lng, const float* __restrict__ lnb,
                const float* __restrict__ bias,
                float* __restrict__ C,                  // logits [M][50]
                const int* __restrict__ pidx,
                unsigned long long* __restrict__ scat) {
  constexpr int NS = 16;
  __shared__ __align__(16) unsigned char smem[36864];
  const int tid = threadIdx.x;
  const int lane = tid & 63, w = tid >> 6;
  const int cpx = gridDim.x >> 3;
  const int bm = (blockIdx.x & 7) * cpx + (blockIdx.x >> 3);

  const int sslot = (tid & 3) ^ ((tid >> 3) & 3);
  const int srow = tid >> 2;                            // 0..127
  const unsigned short* aG = A + (size_t)(bm * 128 + srow) * 512 + sslot * 8;
  const unsigned char* bG = (const unsigned char*)Bt + (size_t)srow * 1024 + sslot * 16;
  unsigned char* laBase = smem + srow * 64 + (tid & 3) * 16;
  unsigned char* lbBase = smem + 16384 + w * 1024;

  if (w < 4) {
    const float* src = (w < 2) ? (lng + w * 256 + lane * 4)
                               : (lnb + (w - 2) * 256 + lane * 4);
    unsigned char* dst = smem + 32768 + ((w < 2) ? w * 1024 : 2048 + (w - 2) * 1024);
    async_copy16(src, dst);
  }
  asm volatile("s_waitcnt vmcnt(0)" ::: "memory");
  __builtin_amdgcn_s_barrier();

  float ssum = 0.f, ssq = 0.f;
  {
    const float2* sp = statsIn + (size_t)(bm * 128 + srow) * 8;
#pragma unroll
    for (int j = 0; j < 8; j++) { float2 p = sp[j]; ssum += p.x; ssq += p.y; }
  }
  const float mu = ssum * (1.f / 512.f);
  const float rs = rsqrtf(ssq * (1.f / 512.f) - mu * mu + 1e-5f);
  const float* gl = (const float*)(smem + 32768);
  const float* bl = (const float*)(smem + 34816);

  uint4 ra0, ra1;
  auto issueA = [&](int s, uint4* ra) { *ra = *(const uint4*)(aG + (size_t)s * 32); };
  auto issueB = [&](int s) {
    async_copy16(bG + (size_t)s * 64, lbBase + (s & 1) * 8192);
  };
  auto writeA = [&](int s, const uint4* ra) {
    const int slot = s & 1;
    const int k0 = s * 32 + sslot * 8;
    float x[8]; unpack8(*ra, x);
    float4 g0 = *(const float4*)(gl + k0), g1 = *(const float4*)(gl + k0 + 4);
    float4 t0 = *(const float4*)(bl + k0), t1 = *(const float4*)(bl + k0 + 4);
    float y0 = fmaxf(fmaf((x[0] - mu) * rs, g0.x, t0.x), 0.f);
    float y1 = fmaxf(fmaf((x[1] - mu) * rs, g0.y, t0.y), 0.f);
    float y2 = fmaxf(fmaf((x[2] - mu) * rs, g0.z, t0.z), 0.f);
    float y3 = fmaxf(fmaf((x[3] - mu) * rs, g0.w, t0.w), 0.f);
    float y4 = fmaxf(fmaf((x[4] - mu) * rs, g1.x, t1.x), 0.f);
    float y5 = fmaxf(fmaf((x[5] - mu) * rs, g1.y, t1.y), 0.f);
    float y6 = fmaxf(fmaf((x[6] - mu) * rs, g1.z, t1.z), 0.f);
    float y7 = fmaxf(fmaf((x[7] - mu) * rs, g1.w, t1.w), 0.f);
    uint4 u;
    u.x = pack2(y0, y1); u.y = pack2(y2, y3);
    u.z = pack2(y4, y5); u.w = pack2(y6, y7);
    *(uint4*)(laBase + slot * 8192) = u;
  };

  const int wm = w >> 1, wn = w & 1;                    // 4M x 2N waves, 32x64 each
  const int frow = lane & 15;
  const int colb = (((lane >> 4) ^ ((frow >> 1) & 3)) << 4);
  const int aRowB = (wm * 32 + frow) * 64;
  const int bRowB = (wn * 64 + frow) * 64;

  f32x4 acc[2][4];
#pragma unroll
  for (int m = 0; m < 2; m++)
#pragma unroll
    for (int n = 0; n < 4; n++) acc[m][n] = (f32x4){0.f, 0.f, 0.f, 0.f};

  issueA(0, &ra0); issueB(0);
  issueA(1, &ra1); issueB(1);

#pragma unroll 1
  for (int s = 0; s < NS; s += 2) {
#pragma unroll
    for (int half = 0; half < 2; half++) {
      const int sc = s + half;
      uint4* raC = half ? &ra1 : &ra0;
      if (sc == NS - 1) asm volatile("s_waitcnt vmcnt(0)" ::: "memory");
      else              asm volatile("s_waitcnt vmcnt(2)" ::: "memory");
      __builtin_amdgcn_sched_barrier(0);
      writeA(sc, raC);
      if (sc + 2 < NS) issueA(sc + 2, raC);
      asm volatile("s_waitcnt lgkmcnt(0)" ::: "memory");
      __builtin_amdgcn_s_barrier();
      __builtin_amdgcn_sched_barrier(0);
      const unsigned char* ab = smem + (sc & 1) * 8192;
      const unsigned char* bb = smem + 16384 + (sc & 1) * 8192;
      bf16x8 af[2];
#pragma unroll
      for (int m = 0; m < 2; m++) af[m] = *(const bf16x8*)(ab + aRowB + m * 1024 + colb);
      __builtin_amdgcn_s_setprio(1);
#pragma unroll
      for (int n = 0; n < 4; n++) {
        bf16x8 bf = *(const bf16x8*)(bb + bRowB + n * 1024 + colb);
#pragma unroll
        for (int m = 0; m < 2; m++)
          acc[m][n] = __builtin_amdgcn_mfma_f32_16x16x32_bf16(af[m], bf, acc[m][n], 0, 0, 0);
      }
      __builtin_amdgcn_s_setprio(0);
      __builtin_amdgcn_sched_barrier(0);
      __builtin_amdgcn_s_barrier();
      __builtin_amdgcn_sched_barrier(0);
      if (sc + 2 < NS) issueB(sc + 2);
    }
  }
  const int rb = bm * 128 + wm * 32 + ((lane >> 4) << 2);
  const int cbl = wn * 64 + frow;
#pragma unroll
  for (int n = 0; n < 4; n++) {
    const int col = cbl + n * 16;
    const float bv = (col < OUTC) ? bias[col] : 0.f;
#pragma unroll
    for (int m = 0; m < 2; m++)
#pragma unroll
      for (int i = 0; i < 4; i++) {
        const int row = rb + m * 16 + i;
        if (col < OUTC) C[(size_t)row * OUTC + col] = acc[m][n][i] + bv;
      }
  }
  // fused score: wn==0 waves hold cols 0..63 (all 50 real cols)
  if (wn == 0) {
#pragma unroll
    for (int m = 0; m < 2; m++)
#pragma unroll
      for (int i = 0; i < 4; i++) {
        float mx = -1e30f;
#pragma unroll
        for (int n = 0; n < 4; n++) {
          const int col = n * 16 + frow;
          float v = acc[m][n][i] + ((col < OUTC) ? bias[col] : 0.f);
          if (col < OUTC) mx = fmaxf(mx, v);
        }
        mx = fmaxf(mx, __shfl_xor(mx, 1));
        mx = fmaxf(mx, __shfl_xor(mx, 2));
        mx = fmaxf(mx, __shfl_xor(mx, 4));
        mx = fmaxf(mx, __shfl_xor(mx, 8));
        if (frow == 0) {
          const int row = rb + m * 16 + i;
          float sc = 1.f / (1.f + expf(-mx));
          int b = row >> 12, p = row & 4095;
          int s = pidx[2 * row], o = pidx[2 * row + 1];
          unsigned long long key = (((unsigned long long)(p + 1)) << 32) |
                                   (unsigned long long)__float_as_uint(sc);
          atomicMax(&scat[((size_t)(b * N_ + s) << 7) + o], key);
        }
      }
  }
}

__global__ void relmat_kernel(const unsigned long long* __restrict__ scat, float* __restrict__ out) {
  int i = blockIdx.x * blockDim.x + threadIdx.x;
  if (i >= B_ * N_ * N_) return;
  unsigned long long v = scat[i];
  out[i] = v ? __uint_as_float((unsigned)(v & 0xffffffffu)) : 0.f;
}

extern "C" void kernel_launch(void* const* d_in, const int* in_sizes, int n_in,
                              void* d_out, int out_size, void* d_ws, size_t ws_size,
                              hipStream_t stream) {
  const float* visual_feat = (const float*)d_in[0];
  const float* box_info    = (const float*)d_in[1];
  const float* pred_logits = (const float*)d_in[2];
  const int*   pair_idx    = (const int*)d_in[3];
  const float* obj_sem_w   = (const float*)d_in[4];
  const float* pos_w1 = (const float*)d_in[5];
  const float* pos_b1 = (const float*)d_in[6];
  const float* pos_w2 = (const float*)d_in[7];
  const float* pos_b2 = (const float*)d_in[8];
  const float* vis_w  = (const float*)d_in[9];
  const float* vis_b  = (const float*)d_in[10];
  const float* geo_w  = (const float*)d_in[11];
  const float* geo_b  = (const float*)d_in[12];
  const float* fus_g  = (const float*)d_in[13];
  const float* fus_bt = (const float*)d_in[14];
  const float* fus_w  = (const float*)d_in[15];
  const float* fus_b  = (const float*)d_in[16];
  const float* cls_g  = (const float*)d_in[17];
  const float* cls_bt = (const float*)d_in[18];
  const float* cls_w  = (const float*)d_in[19];
  const float* cls_b  = (const float*)d_in[20];

  char* ws = (char*)d_ws;
  size_t off = 0;
  auto alloc = [&](size_t bytes) { char* p = ws + off; off += (bytes + 255) & ~(size_t)255; return p; };
  unsigned short* fused = (unsigned short*)alloc((size_t)M_ * 1024 * 2);      // 134 MB
  unsigned short* fused2 = (unsigned short*)alloc((size_t)M_ * 512 * 2);      // 67 MB
  unsigned short* nodeFb = (unsigned short*)alloc((size_t)B_ * N_ * NODEF * 2);
  unsigned short* wT_vis = (unsigned short*)alloc((size_t)512 * 1024 * 2);
  unsigned short* wT_geo = (unsigned short*)alloc((size_t)512 * KGEOP * 2);
  unsigned short* wT_fus = (unsigned short*)alloc((size_t)512 * 1024 * 2);
  unsigned short* wT_cls = (unsigned short*)alloc((size_t)128 * 512 * 2);
  unsigned long long* scat = (unsigned long long*)alloc((size_t)B_ * N_ * N_ * 8);
  float2* statsP1 = (float2*)alloc((size_t)M_ * 16 * 8);                      // 8 MB
  float2* statsP2 = (float2*)alloc((size_t)M_ * 8 * 8);                       // 4 MB

  float* out_logits = (float*)d_out;
  float* out_rel = out_logits + (size_t)M_ * OUTC;

  prep_kernel<<<dim3((PREP_TOT + 255) / 256), 256, 0, stream>>>(
      (uint4*)scat, vis_w, wT_vis, geo_w, wT_geo, fus_w, wT_fus, cls_w, wT_cls);
  node_kernel<<<dim3(B_ * N_), 128, 0, stream>>>(box_info, pred_logits, obj_sem_w,
                                                 pos_w1, pos_b1, pos_w2, pos_b2, nodeFb);
  // geo: gather GEMM -> fused[:,512:] + partial row stats (slots 8..15)
  gemm_geo<<<dim3(1024), 512, 0, stream>>>(wT_geo, KGEOP, geo_b,
                                           fused, 1024, 512, KGEOP / 32, 2,
                                           pair_idx, nodeFb, (const unsigned short*)scat,
                                           statsP1);
  // vis: f32+relu GEMM -> fused[:,0:512] + partial row stats (slots 0..7)
  gemm256f3<<<dim3(1024), 512, 0, stream>>>(visual_feat, wT_vis, vis_b,
                                            fused, 1024, 0, 2, statsP1);
  // fus: LN(stats combine)+relu in A-staging -> fused2 + partial stats2 (8 slots)
  gemm_fusLN<<<dim3(1024), 512, 0, stream>>>(fused, wT_fus, statsP1, fus_g, fus_bt,
                                             fus_b, fused2, 2, statsP2);
  // cls: LN(stats2)+relu in A-staging -> logits + fused score scatter
  gemm_clsLN<<<dim3(512), 512, 0, stream>>>(fused2, wT_cls, statsP2, cls_g, cls_bt,
                                            cls_b, out_logits, pair_idx, scat);
  relmat_kernel<<<dim3((B_ * N_ * N_) / 256), 256, 0, stream>>>(scat, out_rel);
}